// Round 1
// baseline (3109.378 us; speedup 1.0000x reference)
//
#include <hip/hip_runtime.h>

// ConvLSTM (B=16,H=128,W=128,CIN=1,HID=64, 2 cells, h=c=0 -> f-gate dead)
// Pipeline: repack -> gates<1> -> attn -> gates<64> -> attn -> outconv
// All fp32 this round. NHWC intermediates (C=64 contiguous).

#define DEVFN __device__ __forceinline__

DEVFN float sigmoidf_(float z) { return 1.0f / (1.0f + __expf(-z)); }

// ---------------------------------------------------------------------------
// Weight repack: pw[g][k][c], g in {ci,co,cg,px,py}, k = pos*CIN + cin, c = hid ch
// Layer1: [5][576][64]; Layer0: [5][9][64]
// ---------------------------------------------------------------------------
__global__ __launch_bounds__(256) void repack_kernel(
    const float* __restrict__ cw0, const float* __restrict__ pxw0, const float* __restrict__ pyw0,
    const float* __restrict__ cw1, const float* __restrict__ pxw1, const float* __restrict__ pyw1,
    float* __restrict__ pw1, float* __restrict__ pw0)
{
    int idx = blockIdx.x * 256 + threadIdx.x;
    if (idx < 5 * 576 * 64) {
        int g = idx / (576 * 64);
        int rem = idx - g * 576 * 64;
        int k = rem >> 6, c = rem & 63;
        int pos = k >> 6, cin = k & 63;  // k = pos*64 + cin
        float v;
        if (g == 0)      v = cw1[((c      ) * 128 + cin) * 9 + pos];  // ci
        else if (g == 1) v = cw1[((128 + c) * 128 + cin) * 9 + pos];  // co
        else if (g == 2) v = cw1[((192 + c) * 128 + cin) * 9 + pos];  // cg
        else if (g == 3) v = pxw1[(c * 64 + cin) * 9 + pos];          // px
        else             v = pyw1[(c * 64 + cin) * 9 + pos];          // py
        pw1[idx] = v;
    } else if (idx < 5 * 576 * 64 + 5 * 9 * 64) {
        int i2 = idx - 5 * 576 * 64;
        int g = i2 / (9 * 64);
        int rem = i2 - g * 9 * 64;
        int pos = rem >> 6, c = rem & 63;
        float v;
        if (g == 0)      v = cw0[(c      ) * 585 + pos];  // conv_w0[c][0][pos], stride 65*9=585
        else if (g == 1) v = cw0[(128 + c) * 585 + pos];
        else if (g == 2) v = cw0[(192 + c) * 585 + pos];
        else if (g == 3) v = pxw0[c * 9 + pos];
        else             v = pyw0[c * 9 + pos];
        pw0[i2] = v;
    }
}

// ---------------------------------------------------------------------------
// Fused gate conv + LSTM pointwise. One block = 64 pixels (half row) x all 64 ch.
// 256 threads: pg = tid&15 (pixels pg, pg+16, pg+32, pg+48), og = tid>>4 (4 ch).
// Per-thread: acc[5 gates][4 px][4 ch]. Patch in LDS, weights from global (L2).
// ---------------------------------------------------------------------------
template <int CIN>
__global__ __launch_bounds__(256) void gates_kernel(
    const float* __restrict__ src,  // [16,128,128,CIN] NHWC
    const float* __restrict__ pw,   // [5][9*CIN][64]
    const float* __restrict__ cb,   // conv_b [256]
    float* __restrict__ dst)        // [16,128,128,64] NHWC h2pre
{
    constexpr int K = 9 * CIN;
    constexpr int CSTR = (CIN == 64) ? 68 : 1;  // pad 64->68: conflict-free b128 reads
    __shared__ float lds[3 * 66 * CSTR];

    const int tid = threadIdx.x;
    const int bid = blockIdx.x;
    const int xt = bid & 1, y = (bid >> 1) & 127, b = bid >> 8;
    const int x0 = xt * 64;

    if constexpr (CIN == 64) {
        for (int i4 = tid; i4 < 3 * 66 * 16; i4 += 256) {
            int r = i4 / (66 * 16);
            int rem = i4 - r * (66 * 16);
            int xx = rem >> 4, c4 = rem & 15;
            int gy = y + r - 1, gx = x0 + xx - 1;
            float4 v = make_float4(0.f, 0.f, 0.f, 0.f);
            if ((unsigned)gy < 128u && (unsigned)gx < 128u)
                v = *(const float4*)(src + (((b * 128 + gy) * 128 + gx) * 64 + c4 * 4));
            *(float4*)(&lds[(r * 66 + xx) * 68 + c4 * 4]) = v;
        }
    } else {
        for (int i = tid; i < 3 * 66; i += 256) {
            int r = i / 66, xx = i - r * 66;
            int gy = y + r - 1, gx = x0 + xx - 1;
            float v = 0.f;
            if ((unsigned)gy < 128u && (unsigned)gx < 128u)
                v = src[(b * 128 + gy) * 128 + gx];
            lds[r * 66 + xx] = v;
        }
    }
    __syncthreads();

    const int pg = tid & 15, og = tid >> 4;
    const int ch0 = og * 4;

    float acc[5][4][4];
#pragma unroll
    for (int g = 0; g < 5; ++g)
#pragma unroll
        for (int j = 0; j < 4; ++j)
#pragma unroll
            for (int u = 0; u < 4; ++u) acc[g][j][u] = 0.f;

    for (int pos = 0; pos < 9; ++pos) {
        const int dy = pos / 3, dx = pos - dy * 3;
        if constexpr (CIN == 64) {
            for (int c16 = 0; c16 < 16; ++c16) {
                float av[4][4];
#pragma unroll
                for (int j = 0; j < 4; ++j) {
                    const float4 t4 = *(const float4*)(&lds[(dy * 66 + pg + 16 * j + dx) * 68 + c16 * 4]);
                    av[j][0] = t4.x; av[j][1] = t4.y; av[j][2] = t4.z; av[j][3] = t4.w;
                }
#pragma unroll
                for (int g = 0; g < 5; ++g) {
#pragma unroll
                    for (int cc = 0; cc < 4; ++cc) {
                        const float4 w4 = *(const float4*)(pw + ((size_t)(g * K + pos * 64 + c16 * 4 + cc)) * 64 + ch0);
                        const float w0 = w4.x, w1 = w4.y, w2 = w4.z, w3 = w4.w;
#pragma unroll
                        for (int j = 0; j < 4; ++j) {
                            acc[g][j][0] = fmaf(av[j][cc], w0, acc[g][j][0]);
                            acc[g][j][1] = fmaf(av[j][cc], w1, acc[g][j][1]);
                            acc[g][j][2] = fmaf(av[j][cc], w2, acc[g][j][2]);
                            acc[g][j][3] = fmaf(av[j][cc], w3, acc[g][j][3]);
                        }
                    }
                }
            }
        } else {
            float a[4];
#pragma unroll
            for (int j = 0; j < 4; ++j) a[j] = lds[dy * 66 + pg + 16 * j + dx];
#pragma unroll
            for (int g = 0; g < 5; ++g) {
                const float4 w4 = *(const float4*)(pw + (g * 9 + pos) * 64 + ch0);
                const float w0 = w4.x, w1 = w4.y, w2 = w4.z, w3 = w4.w;
#pragma unroll
                for (int j = 0; j < 4; ++j) {
                    acc[g][j][0] = fmaf(a[j], w0, acc[g][j][0]);
                    acc[g][j][1] = fmaf(a[j], w1, acc[g][j][1]);
                    acc[g][j][2] = fmaf(a[j], w2, acc[g][j][2]);
                    acc[g][j][3] = fmaf(a[j], w3, acc[g][j][3]);
                }
            }
        }
    }

    float bci[4], bco[4], bcg[4];
#pragma unroll
    for (int u = 0; u < 4; ++u) {
        bci[u] = cb[ch0 + u];
        bco[u] = cb[128 + ch0 + u];
        bcg[u] = cb[192 + ch0 + u];
    }
    const int rowbase = (b * 128 + y) * 128 + x0;
#pragma unroll
    for (int j = 0; j < 4; ++j) {
        float hv[4];
#pragma unroll
        for (int u = 0; u < 4; ++u) {
            float ci = acc[0][j][u] + bci[u];
            float co = acc[1][j][u] + bco[u];
            float cg = acc[2][j][u] + bcg[u];
            float pxv = acc[3][j][u];
            float pyv = acc[4][j][u];
            float iv = sigmoidf_(ci + pxv);
            float ov = sigmoidf_(co + pyv);
            float gv = tanhf(cg + pyv);
            hv[u] = ov * tanhf(iv * gv);  // c=0 -> c2 = i*g
        }
        *(float4*)(dst + (size_t)(rowbase + pg + 16 * j) * 64 + ch0) = make_float4(hv[0], hv[1], hv[2], hv[3]);
    }
}

// ---------------------------------------------------------------------------
// Window attention: one 8x8 window per 256-thread block (4 waves).
// lane = token. LDS qkv layout [s][h][d][t] (t fastest) -> conflict-free.
// Wave w: qkv outputs [48w,48w+48); attention head w; proj columns [16w,16w+16).
// attn-out (normalized) overwrites the q slot, reused by proj.
// ---------------------------------------------------------------------------
__global__ __launch_bounds__(256) void attn_kernel(
    const float* __restrict__ src,   // h2pre NHWC [16,128,128,64]
    const float* __restrict__ qkvw,  // [192][64]
    const float* __restrict__ projw, // [64][64]
    const float* __restrict__ projb, // [64]
    float* __restrict__ dst)         // NHWC out
{
    __shared__ float smem[3 * 64 * 64];  // 48 KB
    const int tid = threadIdx.x;
    const int lane = tid & 63;
    const int wvu = __builtin_amdgcn_readfirstlane(tid >> 6);
    const int wid = blockIdx.x;
    const int b = wid >> 8, rem = wid & 255, wy = rem >> 4, wx = rem & 15;
    const int ty = lane >> 3, tx = lane & 7;
    const int pix = (b * 128 + wy * 8 + ty) * 128 + (wx * 8 + tx);

    float xr[64];
    {
        const float* xp = src + (size_t)pix * 64;
#pragma unroll
        for (int c4 = 0; c4 < 16; ++c4) {
            float4 v = *(const float4*)(xp + 4 * c4);
            xr[4 * c4 + 0] = v.x; xr[4 * c4 + 1] = v.y;
            xr[4 * c4 + 2] = v.z; xr[4 * c4 + 3] = v.w;
        }
    }
    // qkv: o = s*64 + h*16 + d ; store smem[o*64 + lane]
    for (int oi = 0; oi < 48; ++oi) {
        const int o = wvu * 48 + oi;
        const float* wrow = qkvw + o * 64;
        float a0 = 0, a1 = 0, a2 = 0, a3 = 0;
#pragma unroll
        for (int c4 = 0; c4 < 16; ++c4) {
            float4 w4 = *(const float4*)(wrow + 4 * c4);
            a0 = fmaf(xr[4 * c4 + 0], w4.x, a0);
            a1 = fmaf(xr[4 * c4 + 1], w4.y, a1);
            a2 = fmaf(xr[4 * c4 + 2], w4.z, a2);
            a3 = fmaf(xr[4 * c4 + 3], w4.w, a3);
        }
        smem[o * 64 + lane] = (a0 + a1) + (a2 + a3);
    }
    __syncthreads();

    // head = wvu; lane's q row
    float qd[16];
#pragma unroll
    for (int d = 0; d < 16; ++d) qd[d] = smem[(wvu * 16 + d) * 64 + lane];

    float p[64];
    float m0 = -1e30f, m1 = -1e30f, m2 = -1e30f, m3 = -1e30f;
#pragma unroll
    for (int j = 0; j < 64; ++j) {
        const float* kc = smem + (64 + wvu * 16) * 64 + j;  // k[h][d][j]
        float s0 = 0, s1 = 0, s2 = 0, s3 = 0;
#pragma unroll
        for (int d4 = 0; d4 < 4; ++d4) {
            s0 = fmaf(qd[4 * d4 + 0], kc[(4 * d4 + 0) * 64], s0);
            s1 = fmaf(qd[4 * d4 + 1], kc[(4 * d4 + 1) * 64], s1);
            s2 = fmaf(qd[4 * d4 + 2], kc[(4 * d4 + 2) * 64], s2);
            s3 = fmaf(qd[4 * d4 + 3], kc[(4 * d4 + 3) * 64], s3);
        }
        float s = ((s0 + s1) + (s2 + s3)) * 0.25f;  // HD^-0.5
        p[j] = s;
        if ((j & 3) == 0) m0 = fmaxf(m0, s);
        else if ((j & 3) == 1) m1 = fmaxf(m1, s);
        else if ((j & 3) == 2) m2 = fmaxf(m2, s);
        else m3 = fmaxf(m3, s);
    }
    const float m = fmaxf(fmaxf(m0, m1), fmaxf(m2, m3));
    float t0 = 0, t1 = 0, t2 = 0, t3 = 0;
#pragma unroll
    for (int j = 0; j < 64; j += 4) {
        p[j + 0] = __expf(p[j + 0] - m); t0 += p[j + 0];
        p[j + 1] = __expf(p[j + 1] - m); t1 += p[j + 1];
        p[j + 2] = __expf(p[j + 2] - m); t2 += p[j + 2];
        p[j + 3] = __expf(p[j + 3] - m); t3 += p[j + 3];
    }
    const float rs = 1.0f / ((t0 + t1) + (t2 + t3));

    float od[16];
#pragma unroll
    for (int d = 0; d < 16; ++d) od[d] = 0.f;
#pragma unroll
    for (int j = 0; j < 64; ++j) {
        const float pj = p[j];
        const float* vc = smem + (128 + wvu * 16) * 64 + j;  // v[h][d][j]
#pragma unroll
        for (int d = 0; d < 16; ++d) od[d] = fmaf(pj, vc[d * 64], od[d]);
    }
    // normalized attn-out into this head's q slot (only this wave touches it)
#pragma unroll
    for (int d = 0; d < 16; ++d) smem[(wvu * 16 + d) * 64 + lane] = od[d] * rs;
    __syncthreads();

    float of[64];
#pragma unroll
    for (int dd = 0; dd < 64; ++dd) of[dd] = smem[dd * 64 + lane];
    float outv[16];
    for (int ci = 0; ci < 16; ++ci) {
        const int c = wvu * 16 + ci;
        const float* wrow = projw + c * 64;
        float a0 = 0, a1 = 0, a2 = 0, a3 = 0;
#pragma unroll
        for (int d4 = 0; d4 < 16; ++d4) {
            float4 w4 = *(const float4*)(wrow + 4 * d4);
            a0 = fmaf(of[4 * d4 + 0], w4.x, a0);
            a1 = fmaf(of[4 * d4 + 1], w4.y, a1);
            a2 = fmaf(of[4 * d4 + 2], w4.z, a2);
            a3 = fmaf(of[4 * d4 + 3], w4.w, a3);
        }
        outv[ci] = (a0 + a1) + (a2 + a3) + projb[c];
    }
    float* dp = dst + (size_t)pix * 64 + wvu * 16;
#pragma unroll
    for (int q = 0; q < 4; ++q)
        *(float4*)(dp + 4 * q) = make_float4(outv[4 * q], outv[4 * q + 1], outv[4 * q + 2], outv[4 * q + 3]);
}

// ---------------------------------------------------------------------------
// 1x1 output conv: out[pix] = dot(h1[pix][:], out_w) + out_b
// ---------------------------------------------------------------------------
__global__ __launch_bounds__(256) void outconv_kernel(
    const float* __restrict__ h1, const float* __restrict__ ow,
    const float* __restrict__ ob, float* __restrict__ out)
{
    const int idx = blockIdx.x * 256 + threadIdx.x;
    const float* hp = h1 + (size_t)idx * 64;
    float a0 = 0, a1 = 0, a2 = 0, a3 = 0;
#pragma unroll
    for (int c4 = 0; c4 < 16; ++c4) {
        float4 h4 = *(const float4*)(hp + 4 * c4);
        float4 w4 = *(const float4*)(ow + 4 * c4);
        a0 = fmaf(h4.x, w4.x, a0);
        a1 = fmaf(h4.y, w4.y, a1);
        a2 = fmaf(h4.z, w4.z, a2);
        a3 = fmaf(h4.w, w4.w, a3);
    }
    out[idx] = (a0 + a1) + (a2 + a3) + ob[0];
}

// ---------------------------------------------------------------------------
extern "C" void kernel_launch(void* const* d_in, const int* in_sizes, int n_in,
                              void* d_out, int out_size, void* d_ws, size_t ws_size,
                              hipStream_t stream)
{
    const float* x      = (const float*)d_in[0];
    const float* cw0    = (const float*)d_in[1];
    const float* cb0    = (const float*)d_in[2];
    const float* pxw0   = (const float*)d_in[3];
    const float* pyw0   = (const float*)d_in[4];
    const float* qkvw0  = (const float*)d_in[5];
    const float* projw0 = (const float*)d_in[6];
    const float* projb0 = (const float*)d_in[7];
    const float* cw1    = (const float*)d_in[8];
    const float* cb1    = (const float*)d_in[9];
    const float* pxw1   = (const float*)d_in[10];
    const float* pyw1   = (const float*)d_in[11];
    const float* qkvw1  = (const float*)d_in[12];
    const float* projw1 = (const float*)d_in[13];
    const float* projb1 = (const float*)d_in[14];
    const float* outw   = (const float*)d_in[15];
    const float* outb   = (const float*)d_in[16];

    const size_t BUF = (size_t)16 * 128 * 128 * 64 * sizeof(float);  // 64 MB
    char* ws = (char*)d_ws;
    float* bufA = (float*)ws;              // h2pre0 / h2pre1
    float* bufB = (float*)(ws + BUF);      // h0 / h1
    float* pw1  = (float*)(ws + 2 * BUF);  // [5][576][64]
    float* pw0  = pw1 + 5 * 576 * 64;      // [5][9][64]

    repack_kernel<<<(5 * 576 * 64 + 5 * 9 * 64 + 255) / 256, 256, 0, stream>>>(
        cw0, pxw0, pyw0, cw1, pxw1, pyw1, pw1, pw0);

    gates_kernel<1><<<4096, 256, 0, stream>>>(x, pw0, cb0, bufA);
    attn_kernel<<<4096, 256, 0, stream>>>(bufA, qkvw0, projw0, projb0, bufB);
    gates_kernel<64><<<4096, 256, 0, stream>>>(bufB, pw1, cb1, bufA);
    attn_kernel<<<4096, 256, 0, stream>>>(bufA, qkvw1, projw1, projb1, bufB);
    outconv_kernel<<<1024, 256, 0, stream>>>(bufB, outw, outb, (float*)d_out);
}

// Round 2
// 1051.211 us; speedup vs baseline: 2.9579x; 2.9579x over previous
//
#include <hip/hip_runtime.h>

// ConvLSTM (B=16,H=128,W=128,CIN=1,HID=64, 2 cells, h=c=0 -> f-gate dead)
// Pipeline: repack -> gates1(fp32) -> attn -> gates64(bf16 MFMA) -> attn -> outconv

#define DEVFN __device__ __forceinline__

typedef __attribute__((ext_vector_type(8))) short short8;
typedef __attribute__((ext_vector_type(4))) float f32x4;

DEVFN float sigmoidf_(float z) { return 1.0f / (1.0f + __expf(-z)); }

DEVFN unsigned short f2bf(float f) {  // RNE fp32 -> bf16
    unsigned int u = __builtin_bit_cast(unsigned int, f);
    u += 0x7fffu + ((u >> 16) & 1u);
    return (unsigned short)(u >> 16);
}

// ---------------------------------------------------------------------------
// Repack:
//  pwb1 (bf16) [320][576]: n = g*64+c (g in {ci,co,cg,px,py}), k = pos*64+cin
//  pw0  (fp32) [5][9][64]: layer-0 weights, cin=0 slice of conv_w0 + px/py
// ---------------------------------------------------------------------------
__global__ __launch_bounds__(256) void repack_kernel(
    const float* __restrict__ cw0, const float* __restrict__ pxw0, const float* __restrict__ pyw0,
    const float* __restrict__ cw1, const float* __restrict__ pxw1, const float* __restrict__ pyw1,
    unsigned short* __restrict__ pwb1, float* __restrict__ pw0)
{
    int idx = blockIdx.x * 256 + threadIdx.x;
    if (idx < 320 * 576) {
        int n = idx / 576, k = idx - n * 576;
        int g = n >> 6, c = n & 63;
        int pos = k >> 6, cin = k & 63;
        float v;
        if (g == 0)      v = cw1[((c      ) * 128 + cin) * 9 + pos];  // ci
        else if (g == 1) v = cw1[((128 + c) * 128 + cin) * 9 + pos];  // co
        else if (g == 2) v = cw1[((192 + c) * 128 + cin) * 9 + pos];  // cg
        else if (g == 3) v = pxw1[(c * 64 + cin) * 9 + pos];          // px
        else             v = pyw1[(c * 64 + cin) * 9 + pos];          // py
        pwb1[idx] = f2bf(v);
    } else if (idx < 320 * 576 + 5 * 9 * 64) {
        int i2 = idx - 320 * 576;
        int g = i2 / (9 * 64);
        int rem = i2 - g * (9 * 64);
        int pos = rem >> 6, c = rem & 63;
        float v;
        if (g == 0)      v = cw0[(c      ) * 585 + pos];  // conv_w0[c][0][pos], stride 65*9
        else if (g == 1) v = cw0[(128 + c) * 585 + pos];
        else if (g == 2) v = cw0[(192 + c) * 585 + pos];
        else if (g == 3) v = pxw0[c * 9 + pos];
        else             v = pyw0[c * 9 + pos];
        pw0[i2] = v;
    }
}

// ---------------------------------------------------------------------------
// Layer-0 gates (CIN=1): trivial compute, memory-bound. 1 pixel x 4 ch/thread,
// 20 accumulators (no spill). Input is 1 MB -> L1/L2 resident.
// ---------------------------------------------------------------------------
__global__ __launch_bounds__(256) void gates1_kernel(
    const float* __restrict__ x,   // [16,128,128] fp32
    const float* __restrict__ pw,  // [5][9][64]
    const float* __restrict__ cb,  // [256]
    float* __restrict__ dst)       // [16,128,128,64]
{
    const int idx = blockIdx.x * 256 + threadIdx.x;
    const int pix = idx >> 4, ch0 = (idx & 15) * 4;
    const int b = pix >> 14, y = (pix >> 7) & 127, xq = pix & 127;

    float a[9];
#pragma unroll
    for (int dy = 0; dy < 3; ++dy)
#pragma unroll
        for (int dx = 0; dx < 3; ++dx) {
            int gy = y + dy - 1, gx = xq + dx - 1;
            a[dy * 3 + dx] = ((unsigned)gy < 128u && (unsigned)gx < 128u)
                ? x[(b * 128 + gy) * 128 + gx] : 0.f;
        }

    float acc[5][4];
#pragma unroll
    for (int g = 0; g < 5; ++g)
#pragma unroll
        for (int u = 0; u < 4; ++u) acc[g][u] = 0.f;

#pragma unroll
    for (int pos = 0; pos < 9; ++pos) {
        const float av = a[pos];
#pragma unroll
        for (int g = 0; g < 5; ++g) {
            const float4 w4 = *(const float4*)(pw + (g * 9 + pos) * 64 + ch0);
            acc[g][0] = fmaf(av, w4.x, acc[g][0]);
            acc[g][1] = fmaf(av, w4.y, acc[g][1]);
            acc[g][2] = fmaf(av, w4.z, acc[g][2]);
            acc[g][3] = fmaf(av, w4.w, acc[g][3]);
        }
    }

    float hv[4];
#pragma unroll
    for (int u = 0; u < 4; ++u) {
        float ci = acc[0][u] + cb[ch0 + u];
        float co = acc[1][u] + cb[128 + ch0 + u];
        float cg = acc[2][u] + cb[192 + ch0 + u];
        float iv = sigmoidf_(ci + acc[3][u]);
        float ov = sigmoidf_(co + acc[4][u]);
        float gv = tanhf(cg + acc[4][u]);
        hv[u] = ov * tanhf(iv * gv);
    }
    *(float4*)(dst + (size_t)pix * 64 + ch0) = make_float4(hv[0], hv[1], hv[2], hv[3]);
}

// ---------------------------------------------------------------------------
// Layer-1 gates: bf16 MFMA implicit GEMM. M=64 px/block, N=320 (5 gates x 64ch),
// K=576 (9 pos x 64 cin). 4 waves; wave w owns ch [16w,16w+16) of ALL 5 gates
// -> LSTM epilogue is register-local. A: fp32 src -> bf16 LDS [3][66] rows x
// 128B, XOR-swizzled ((xx&7)<<4). B: bf16 [320][576] from L2.
// ---------------------------------------------------------------------------
__global__ __launch_bounds__(256, 2) void gates64_kernel(
    const float* __restrict__ src,          // [16,128,128,64] fp32
    const unsigned short* __restrict__ wtb, // [320][576] bf16
    const float* __restrict__ cb,           // [256]
    float* __restrict__ dst)                // [16,128,128,64] fp32
{
    __shared__ unsigned short lds[3 * 66 * 64];  // 25344 B
    char* const sbase = (char*)lds;

    const int tid = threadIdx.x;
    const int bid = blockIdx.x;
    const int xt = bid & 1, y = (bid >> 1) & 127, b = bid >> 8;
    const int x0 = xt * 64;

    // --- stage A: fp32 -> bf16, swizzled ---
    for (int i4 = tid; i4 < 3 * 66 * 8; i4 += 256) {
        int r = i4 / (66 * 8);
        int rem = i4 - r * (66 * 8);
        int xx = rem >> 3, c8 = rem & 7;
        int gy = y + r - 1, gx = x0 + xx - 1;
        uint4 wv = make_uint4(0, 0, 0, 0);
        if ((unsigned)gy < 128u && (unsigned)gx < 128u) {
            const float* sp = src + (((size_t)(b * 128 + gy) * 128 + gx) * 64 + c8 * 8);
            float4 v0 = *(const float4*)(sp);
            float4 v1 = *(const float4*)(sp + 4);
            wv.x = (unsigned)f2bf(v0.x) | ((unsigned)f2bf(v0.y) << 16);
            wv.y = (unsigned)f2bf(v0.z) | ((unsigned)f2bf(v0.w) << 16);
            wv.z = (unsigned)f2bf(v1.x) | ((unsigned)f2bf(v1.y) << 16);
            wv.w = (unsigned)f2bf(v1.z) | ((unsigned)f2bf(v1.w) << 16);
        }
        int addr = ((r * 66 + xx) * 128 + c8 * 16) ^ ((xx & 7) << 4);
        *(uint4*)(sbase + addr) = wv;
    }
    __syncthreads();

    const int lane = tid & 63;
    const int wv_ = tid >> 6;           // wave id 0..3
    const int r0 = lane & 15;
    const int hi = lane >> 4;
    const int wch = wv_ * 16 + r0;      // output hidden channel

    const unsigned short* bp[5];
#pragma unroll
    for (int g = 0; g < 5; ++g)
        bp[g] = wtb + (size_t)(g * 64 + wch) * 576 + hi * 8;

    f32x4 acc[4][5];
#pragma unroll
    for (int mt = 0; mt < 4; ++mt)
#pragma unroll
        for (int g = 0; g < 5; ++g) acc[mt][g] = (f32x4){0.f, 0.f, 0.f, 0.f};

#pragma unroll
    for (int kk = 0; kk < 18; ++kk) {
        const int pos = kk >> 1, dy = pos / 3, dx = pos % 3, chalf = kk & 1;
        const int swz = (((r0 + dx) & 7) << 4);
        short8 afr[4];
#pragma unroll
        for (int mt = 0; mt < 4; ++mt) {
            const int row = dy * 66 + mt * 16 + r0 + dx;
            const int addr = (row * 128 + chalf * 64 + hi * 16) ^ swz;
            afr[mt] = *(const short8*)(sbase + addr);
        }
        short8 bfr[5];
#pragma unroll
        for (int g = 0; g < 5; ++g)
            bfr[g] = *(const short8*)(bp[g] + kk * 32);
#pragma unroll
        for (int mt = 0; mt < 4; ++mt)
#pragma unroll
            for (int g = 0; g < 5; ++g)
                acc[mt][g] = __builtin_amdgcn_mfma_f32_16x16x32_bf16(
                    afr[mt], bfr[g], acc[mt][g], 0, 0, 0);
    }

    const float bci = cb[wch], bco = cb[128 + wch], bcg = cb[192 + wch];
    const int rowbase = (b * 128 + y) * 128 + x0;
#pragma unroll
    for (int mt = 0; mt < 4; ++mt) {
#pragma unroll
        for (int rg = 0; rg < 4; ++rg) {
            const int px_i = mt * 16 + hi * 4 + rg;
            float ci = acc[mt][0][rg] + bci;
            float co = acc[mt][1][rg] + bco;
            float cg = acc[mt][2][rg] + bcg;
            float pxv = acc[mt][3][rg];
            float pyv = acc[mt][4][rg];
            float iv = sigmoidf_(ci + pxv);
            float ov = sigmoidf_(co + pyv);
            float gv = tanhf(cg + pyv);
            dst[(size_t)(rowbase + px_i) * 64 + wch] = ov * tanhf(iv * gv);
        }
    }
}

// ---------------------------------------------------------------------------
// Window attention: one 8x8 window per 256-thread block (4 waves).
// lane = token. LDS qkv layout [s][h][d][t] (t fastest) -> conflict-free.
// ---------------------------------------------------------------------------
__global__ __launch_bounds__(256) void attn_kernel(
    const float* __restrict__ src,   // NHWC [16,128,128,64]
    const float* __restrict__ qkvw,  // [192][64]
    const float* __restrict__ projw, // [64][64]
    const float* __restrict__ projb, // [64]
    float* __restrict__ dst)         // NHWC
{
    __shared__ float smem[3 * 64 * 64];  // 48 KB
    const int tid = threadIdx.x;
    const int lane = tid & 63;
    const int wvu = __builtin_amdgcn_readfirstlane(tid >> 6);
    const int wid = blockIdx.x;
    const int b = wid >> 8, rem = wid & 255, wy = rem >> 4, wx = rem & 15;
    const int ty = lane >> 3, tx = lane & 7;
    const int pix = (b * 128 + wy * 8 + ty) * 128 + (wx * 8 + tx);

    float xr[64];
    {
        const float* xp = src + (size_t)pix * 64;
#pragma unroll
        for (int c4 = 0; c4 < 16; ++c4) {
            float4 v = *(const float4*)(xp + 4 * c4);
            xr[4 * c4 + 0] = v.x; xr[4 * c4 + 1] = v.y;
            xr[4 * c4 + 2] = v.z; xr[4 * c4 + 3] = v.w;
        }
    }
    for (int oi = 0; oi < 48; ++oi) {
        const int o = wvu * 48 + oi;
        const float* wrow = qkvw + o * 64;
        float a0 = 0, a1 = 0, a2 = 0, a3 = 0;
#pragma unroll
        for (int c4 = 0; c4 < 16; ++c4) {
            float4 w4 = *(const float4*)(wrow + 4 * c4);
            a0 = fmaf(xr[4 * c4 + 0], w4.x, a0);
            a1 = fmaf(xr[4 * c4 + 1], w4.y, a1);
            a2 = fmaf(xr[4 * c4 + 2], w4.z, a2);
            a3 = fmaf(xr[4 * c4 + 3], w4.w, a3);
        }
        smem[o * 64 + lane] = (a0 + a1) + (a2 + a3);
    }
    __syncthreads();

    float qd[16];
#pragma unroll
    for (int d = 0; d < 16; ++d) qd[d] = smem[(wvu * 16 + d) * 64 + lane];

    float p[64];
    float m0 = -1e30f, m1 = -1e30f, m2 = -1e30f, m3 = -1e30f;
#pragma unroll
    for (int j = 0; j < 64; ++j) {
        const float* kc = smem + (64 + wvu * 16) * 64 + j;
        float s0 = 0, s1 = 0, s2 = 0, s3 = 0;
#pragma unroll
        for (int d4 = 0; d4 < 4; ++d4) {
            s0 = fmaf(qd[4 * d4 + 0], kc[(4 * d4 + 0) * 64], s0);
            s1 = fmaf(qd[4 * d4 + 1], kc[(4 * d4 + 1) * 64], s1);
            s2 = fmaf(qd[4 * d4 + 2], kc[(4 * d4 + 2) * 64], s2);
            s3 = fmaf(qd[4 * d4 + 3], kc[(4 * d4 + 3) * 64], s3);
        }
        float s = ((s0 + s1) + (s2 + s3)) * 0.25f;
        p[j] = s;
        if ((j & 3) == 0) m0 = fmaxf(m0, s);
        else if ((j & 3) == 1) m1 = fmaxf(m1, s);
        else if ((j & 3) == 2) m2 = fmaxf(m2, s);
        else m3 = fmaxf(m3, s);
    }
    const float m = fmaxf(fmaxf(m0, m1), fmaxf(m2, m3));
    float t0 = 0, t1 = 0, t2 = 0, t3 = 0;
#pragma unroll
    for (int j = 0; j < 64; j += 4) {
        p[j + 0] = __expf(p[j + 0] - m); t0 += p[j + 0];
        p[j + 1] = __expf(p[j + 1] - m); t1 += p[j + 1];
        p[j + 2] = __expf(p[j + 2] - m); t2 += p[j + 2];
        p[j + 3] = __expf(p[j + 3] - m); t3 += p[j + 3];
    }
    const float rs = 1.0f / ((t0 + t1) + (t2 + t3));

    float od[16];
#pragma unroll
    for (int d = 0; d < 16; ++d) od[d] = 0.f;
#pragma unroll
    for (int j = 0; j < 64; ++j) {
        const float pj = p[j];
        const float* vc = smem + (128 + wvu * 16) * 64 + j;
#pragma unroll
        for (int d = 0; d < 16; ++d) od[d] = fmaf(pj, vc[d * 64], od[d]);
    }
#pragma unroll
    for (int d = 0; d < 16; ++d) smem[(wvu * 16 + d) * 64 + lane] = od[d] * rs;
    __syncthreads();

    float of[64];
#pragma unroll
    for (int dd = 0; dd < 64; ++dd) of[dd] = smem[dd * 64 + lane];
    float outv[16];
    for (int ci = 0; ci < 16; ++ci) {
        const int c = wvu * 16 + ci;
        const float* wrow = projw + c * 64;
        float a0 = 0, a1 = 0, a2 = 0, a3 = 0;
#pragma unroll
        for (int d4 = 0; d4 < 16; ++d4) {
            float4 w4 = *(const float4*)(wrow + 4 * d4);
            a0 = fmaf(of[4 * d4 + 0], w4.x, a0);
            a1 = fmaf(of[4 * d4 + 1], w4.y, a1);
            a2 = fmaf(of[4 * d4 + 2], w4.z, a2);
            a3 = fmaf(of[4 * d4 + 3], w4.w, a3);
        }
        outv[ci] = (a0 + a1) + (a2 + a3) + projb[c];
    }
    float* dp = dst + (size_t)pix * 64 + wvu * 16;
#pragma unroll
    for (int q = 0; q < 4; ++q)
        *(float4*)(dp + 4 * q) = make_float4(outv[4 * q], outv[4 * q + 1], outv[4 * q + 2], outv[4 * q + 3]);
}

// ---------------------------------------------------------------------------
__global__ __launch_bounds__(256) void outconv_kernel(
    const float* __restrict__ h1, const float* __restrict__ ow,
    const float* __restrict__ ob, float* __restrict__ out)
{
    const int idx = blockIdx.x * 256 + threadIdx.x;
    const float* hp = h1 + (size_t)idx * 64;
    float a0 = 0, a1 = 0, a2 = 0, a3 = 0;
#pragma unroll
    for (int c4 = 0; c4 < 16; ++c4) {
        float4 h4 = *(const float4*)(hp + 4 * c4);
        float4 w4 = *(const float4*)(ow + 4 * c4);
        a0 = fmaf(h4.x, w4.x, a0);
        a1 = fmaf(h4.y, w4.y, a1);
        a2 = fmaf(h4.z, w4.z, a2);
        a3 = fmaf(h4.w, w4.w, a3);
    }
    out[idx] = (a0 + a1) + (a2 + a3) + ob[0];
}

// ---------------------------------------------------------------------------
extern "C" void kernel_launch(void* const* d_in, const int* in_sizes, int n_in,
                              void* d_out, int out_size, void* d_ws, size_t ws_size,
                              hipStream_t stream)
{
    const float* x      = (const float*)d_in[0];
    const float* cw0    = (const float*)d_in[1];
    const float* cb0    = (const float*)d_in[2];
    const float* pxw0   = (const float*)d_in[3];
    const float* pyw0   = (const float*)d_in[4];
    const float* qkvw0  = (const float*)d_in[5];
    const float* projw0 = (const float*)d_in[6];
    const float* projb0 = (const float*)d_in[7];
    const float* cw1    = (const float*)d_in[8];
    const float* cb1    = (const float*)d_in[9];
    const float* pxw1   = (const float*)d_in[10];
    const float* pyw1   = (const float*)d_in[11];
    const float* qkvw1  = (const float*)d_in[12];
    const float* projw1 = (const float*)d_in[13];
    const float* projb1 = (const float*)d_in[14];
    const float* outw   = (const float*)d_in[15];
    const float* outb   = (const float*)d_in[16];

    const size_t BUF = (size_t)16 * 128 * 128 * 64 * sizeof(float);  // 64 MB
    char* ws = (char*)d_ws;
    float* bufA = (float*)ws;                         // h2pre0 / h2pre1
    float* bufB = (float*)(ws + BUF);                 // h0 / h1
    unsigned short* pwb1 = (unsigned short*)(ws + 2 * BUF);   // [320][576] bf16
    float* pw0 = (float*)(ws + 2 * BUF + 400 * 1024);         // [5][9][64] fp32

    repack_kernel<<<(320 * 576 + 5 * 9 * 64 + 255) / 256, 256, 0, stream>>>(
        cw0, pxw0, pyw0, cw1, pxw1, pyw1, pwb1, pw0);

    gates1_kernel<<<16384, 256, 0, stream>>>(x, pw0, cb0, bufA);
    attn_kernel<<<4096, 256, 0, stream>>>(bufA, qkvw0, projw0, projb0, bufB);
    gates64_kernel<<<4096, 256, 0, stream>>>(bufB, pwb1, cb1, bufA);
    attn_kernel<<<4096, 256, 0, stream>>>(bufA, qkvw1, projw1, projb1, bufB);
    outconv_kernel<<<1024, 256, 0, stream>>>(bufB, outw, outb, (float*)d_out);
}

// Round 3
// 778.316 us; speedup vs baseline: 3.9950x; 1.3506x over previous
//
#include <hip/hip_runtime.h>

// ConvLSTM (B=16,H=128,W=128,CIN=1,HID=64, 2 cells, h=c=0 -> f-gate dead)
// Pipeline: repack -> gates1(fp32) -> attn -> gates64(bf16 MFMA) -> attn -> outconv
// attn: per-window block, wave w owns head w end-to-end; LDS [sec][d4][t][4f]
// layout gives b128 broadcasts for k/v and conflict-free strided lane rows.

#define DEVFN __device__ __forceinline__

typedef __attribute__((ext_vector_type(8))) short short8;
typedef __attribute__((ext_vector_type(4))) float f32x4;

DEVFN float sigmoidf_(float z) { return 1.0f / (1.0f + __expf(-z)); }

DEVFN unsigned short f2bf(float f) {  // RNE fp32 -> bf16
    unsigned int u = __builtin_bit_cast(unsigned int, f);
    u += 0x7fffu + ((u >> 16) & 1u);
    return (unsigned short)(u >> 16);
}

// ---------------------------------------------------------------------------
// Repack:
//  pwb1 (bf16) [320][576]: n = g*64+c (g in {ci,co,cg,px,py}), k = pos*64+cin
//  pw0  (fp32) [5][9][64]: layer-0 weights, cin=0 slice of conv_w0 + px/py
// ---------------------------------------------------------------------------
__global__ __launch_bounds__(256) void repack_kernel(
    const float* __restrict__ cw0, const float* __restrict__ pxw0, const float* __restrict__ pyw0,
    const float* __restrict__ cw1, const float* __restrict__ pxw1, const float* __restrict__ pyw1,
    unsigned short* __restrict__ pwb1, float* __restrict__ pw0)
{
    int idx = blockIdx.x * 256 + threadIdx.x;
    if (idx < 320 * 576) {
        int n = idx / 576, k = idx - n * 576;
        int g = n >> 6, c = n & 63;
        int pos = k >> 6, cin = k & 63;
        float v;
        if (g == 0)      v = cw1[((c      ) * 128 + cin) * 9 + pos];  // ci
        else if (g == 1) v = cw1[((128 + c) * 128 + cin) * 9 + pos];  // co
        else if (g == 2) v = cw1[((192 + c) * 128 + cin) * 9 + pos];  // cg
        else if (g == 3) v = pxw1[(c * 64 + cin) * 9 + pos];          // px
        else             v = pyw1[(c * 64 + cin) * 9 + pos];          // py
        pwb1[idx] = f2bf(v);
    } else if (idx < 320 * 576 + 5 * 9 * 64) {
        int i2 = idx - 320 * 576;
        int g = i2 / (9 * 64);
        int rem = i2 - g * (9 * 64);
        int pos = rem >> 6, c = rem & 63;
        float v;
        if (g == 0)      v = cw0[(c      ) * 585 + pos];  // conv_w0[c][0][pos], stride 65*9
        else if (g == 1) v = cw0[(128 + c) * 585 + pos];
        else if (g == 2) v = cw0[(192 + c) * 585 + pos];
        else if (g == 3) v = pxw0[c * 9 + pos];
        else             v = pyw0[c * 9 + pos];
        pw0[i2] = v;
    }
}

// ---------------------------------------------------------------------------
// Layer-0 gates (CIN=1): memory-bound. 1 pixel x 4 ch/thread.
// ---------------------------------------------------------------------------
__global__ __launch_bounds__(256) void gates1_kernel(
    const float* __restrict__ x,   // [16,128,128] fp32
    const float* __restrict__ pw,  // [5][9][64]
    const float* __restrict__ cb,  // [256]
    float* __restrict__ dst)       // [16,128,128,64]
{
    const int idx = blockIdx.x * 256 + threadIdx.x;
    const int pix = idx >> 4, ch0 = (idx & 15) * 4;
    const int b = pix >> 14, y = (pix >> 7) & 127, xq = pix & 127;

    float a[9];
#pragma unroll
    for (int dy = 0; dy < 3; ++dy)
#pragma unroll
        for (int dx = 0; dx < 3; ++dx) {
            int gy = y + dy - 1, gx = xq + dx - 1;
            a[dy * 3 + dx] = ((unsigned)gy < 128u && (unsigned)gx < 128u)
                ? x[(b * 128 + gy) * 128 + gx] : 0.f;
        }

    float acc[5][4];
#pragma unroll
    for (int g = 0; g < 5; ++g)
#pragma unroll
        for (int u = 0; u < 4; ++u) acc[g][u] = 0.f;

#pragma unroll
    for (int pos = 0; pos < 9; ++pos) {
        const float av = a[pos];
#pragma unroll
        for (int g = 0; g < 5; ++g) {
            const float4 w4 = *(const float4*)(pw + (g * 9 + pos) * 64 + ch0);
            acc[g][0] = fmaf(av, w4.x, acc[g][0]);
            acc[g][1] = fmaf(av, w4.y, acc[g][1]);
            acc[g][2] = fmaf(av, w4.z, acc[g][2]);
            acc[g][3] = fmaf(av, w4.w, acc[g][3]);
        }
    }

    float hv[4];
#pragma unroll
    for (int u = 0; u < 4; ++u) {
        float ci = acc[0][u] + cb[ch0 + u];
        float co = acc[1][u] + cb[128 + ch0 + u];
        float cg = acc[2][u] + cb[192 + ch0 + u];
        float iv = sigmoidf_(ci + acc[3][u]);
        float ov = sigmoidf_(co + acc[4][u]);
        float gv = tanhf(cg + acc[4][u]);
        hv[u] = ov * tanhf(iv * gv);
    }
    *(float4*)(dst + (size_t)pix * 64 + ch0) = make_float4(hv[0], hv[1], hv[2], hv[3]);
}

// ---------------------------------------------------------------------------
// Layer-1 gates: bf16 MFMA implicit GEMM (verified round 2).
// ---------------------------------------------------------------------------
__global__ __launch_bounds__(256, 2) void gates64_kernel(
    const float* __restrict__ src,          // [16,128,128,64] fp32
    const unsigned short* __restrict__ wtb, // [320][576] bf16
    const float* __restrict__ cb,           // [256]
    float* __restrict__ dst)                // [16,128,128,64] fp32
{
    __shared__ unsigned short lds[3 * 66 * 64];  // 25344 B
    char* const sbase = (char*)lds;

    const int tid = threadIdx.x;
    const int bid = blockIdx.x;
    const int xt = bid & 1, y = (bid >> 1) & 127, b = bid >> 8;
    const int x0 = xt * 64;

    for (int i4 = tid; i4 < 3 * 66 * 8; i4 += 256) {
        int r = i4 / (66 * 8);
        int rem = i4 - r * (66 * 8);
        int xx = rem >> 3, c8 = rem & 7;
        int gy = y + r - 1, gx = x0 + xx - 1;
        uint4 wv = make_uint4(0, 0, 0, 0);
        if ((unsigned)gy < 128u && (unsigned)gx < 128u) {
            const float* sp = src + (((size_t)(b * 128 + gy) * 128 + gx) * 64 + c8 * 8);
            float4 v0 = *(const float4*)(sp);
            float4 v1 = *(const float4*)(sp + 4);
            wv.x = (unsigned)f2bf(v0.x) | ((unsigned)f2bf(v0.y) << 16);
            wv.y = (unsigned)f2bf(v0.z) | ((unsigned)f2bf(v0.w) << 16);
            wv.z = (unsigned)f2bf(v1.x) | ((unsigned)f2bf(v1.y) << 16);
            wv.w = (unsigned)f2bf(v1.z) | ((unsigned)f2bf(v1.w) << 16);
        }
        int addr = ((r * 66 + xx) * 128 + c8 * 16) ^ ((xx & 7) << 4);
        *(uint4*)(sbase + addr) = wv;
    }
    __syncthreads();

    const int lane = tid & 63;
    const int wv_ = tid >> 6;
    const int r0 = lane & 15;
    const int hi = lane >> 4;
    const int wch = wv_ * 16 + r0;

    const unsigned short* bp[5];
#pragma unroll
    for (int g = 0; g < 5; ++g)
        bp[g] = wtb + (size_t)(g * 64 + wch) * 576 + hi * 8;

    f32x4 acc[4][5];
#pragma unroll
    for (int mt = 0; mt < 4; ++mt)
#pragma unroll
        for (int g = 0; g < 5; ++g) acc[mt][g] = (f32x4){0.f, 0.f, 0.f, 0.f};

#pragma unroll
    for (int kk = 0; kk < 18; ++kk) {
        const int pos = kk >> 1, dy = pos / 3, dx = pos % 3, chalf = kk & 1;
        const int swz = (((r0 + dx) & 7) << 4);
        short8 afr[4];
#pragma unroll
        for (int mt = 0; mt < 4; ++mt) {
            const int row = dy * 66 + mt * 16 + r0 + dx;
            const int addr = (row * 128 + chalf * 64 + hi * 16) ^ swz;
            afr[mt] = *(const short8*)(sbase + addr);
        }
        short8 bfr[5];
#pragma unroll
        for (int g = 0; g < 5; ++g)
            bfr[g] = *(const short8*)(bp[g] + kk * 32);
#pragma unroll
        for (int mt = 0; mt < 4; ++mt)
#pragma unroll
            for (int g = 0; g < 5; ++g)
                acc[mt][g] = __builtin_amdgcn_mfma_f32_16x16x32_bf16(
                    afr[mt], bfr[g], acc[mt][g], 0, 0, 0);
    }

    const float bci = cb[wch], bco = cb[128 + wch], bcg = cb[192 + wch];
    const int rowbase = (b * 128 + y) * 128 + x0;
#pragma unroll
    for (int mt = 0; mt < 4; ++mt) {
#pragma unroll
        for (int rg = 0; rg < 4; ++rg) {
            const int px_i = mt * 16 + hi * 4 + rg;
            float ci = acc[mt][0][rg] + bci;
            float co = acc[mt][1][rg] + bco;
            float cg = acc[mt][2][rg] + bcg;
            float pxv = acc[mt][3][rg];
            float pyv = acc[mt][4][rg];
            float iv = sigmoidf_(ci + pxv);
            float ov = sigmoidf_(co + pyv);
            float gv = tanhf(cg + pyv);
            dst[(size_t)(rowbase + px_i) * 64 + wch] = ov * tanhf(iv * gv);
        }
    }
}

// ---------------------------------------------------------------------------
// Window attention v2. One 8x8 window per 256-thread block; wave w = head w.
// LDS: smem[sec][d4][t][4] floats, sec = s*4+h (s in {q,k,v}), 48 KB.
//  - per-lane rows (q/of/qkv writes): 16B lane stride -> conflict-free
//  - k/v rows: 4x b128 uniform broadcast per token (was 16x b32)
// Wave w computes q,k,v of head w itself -> no barrier until proj.
// ---------------------------------------------------------------------------
__global__ __launch_bounds__(256, 3) void attn_kernel(
    const float* __restrict__ src,   // NHWC [16,128,128,64]
    const float* __restrict__ qkvw,  // [192][64]
    const float* __restrict__ projw, // [64][64]
    const float* __restrict__ projb, // [64]
    float* __restrict__ dst)         // NHWC
{
    __shared__ float smem[12 * 4 * 64 * 4];  // 49152 B
    const int tid = threadIdx.x;
    const int lane = tid & 63;
    const int w = __builtin_amdgcn_readfirstlane(tid >> 6);
    const int wid = blockIdx.x;
    const int b = wid >> 8, rem = wid & 255, wy = rem >> 4, wx = rem & 15;
    const int ty = lane >> 3, tx = lane & 7;
    const int pix = (b * 128 + wy * 8 + ty) * 128 + (wx * 8 + tx);

    // ---- load X row (own token, all 64 ch) ----
    float xr[64];
    {
        const float* xp = src + (size_t)pix * 64;
#pragma unroll
        for (int c4 = 0; c4 < 16; ++c4) {
            float4 v = *(const float4*)(xp + 4 * c4);
            xr[4 * c4 + 0] = v.x; xr[4 * c4 + 1] = v.y;
            xr[4 * c4 + 2] = v.z; xr[4 * c4 + 3] = v.w;
        }
    }

    // ---- phase 1: qkv for head w (s = g in {0,1,2}), weights via s_load ----
    for (int g = 0; g < 3; ++g) {
        float acc[16];
#pragma unroll
        for (int d = 0; d < 16; ++d) {
            const float* wrow = qkvw + (g * 64 + w * 16 + d) * 64;
            float a0 = 0, a1 = 0, a2 = 0, a3 = 0;
#pragma unroll
            for (int c4 = 0; c4 < 16; ++c4) {
                float4 w4 = *(const float4*)(wrow + 4 * c4);
                a0 = fmaf(xr[4 * c4 + 0], w4.x, a0);
                a1 = fmaf(xr[4 * c4 + 1], w4.y, a1);
                a2 = fmaf(xr[4 * c4 + 2], w4.z, a2);
                a3 = fmaf(xr[4 * c4 + 3], w4.w, a3);
            }
            acc[d] = (a0 + a1) + (a2 + a3);
        }
        const int sec = g * 4 + w;
#pragma unroll
        for (int d4 = 0; d4 < 4; ++d4)
            *(float4*)(smem + ((sec * 4 + d4) * 64 + lane) * 4) =
                make_float4(acc[4 * d4], acc[4 * d4 + 1], acc[4 * d4 + 2], acc[4 * d4 + 3]);
    }

    // ---- phase 2: scores + softmax (head w, own token = query) ----
    float qd[16];
#pragma unroll
    for (int d4 = 0; d4 < 4; ++d4) {
        float4 v = *(const float4*)(smem + ((w * 4 + d4) * 64 + lane) * 4);
        qd[4 * d4 + 0] = v.x; qd[4 * d4 + 1] = v.y;
        qd[4 * d4 + 2] = v.z; qd[4 * d4 + 3] = v.w;
    }
    const float* kb = smem + ((4 + w) * 4) * 64 * 4;  // k section, head w
    float p[64];
    float m0 = -1e30f, m1 = -1e30f, m2 = -1e30f, m3 = -1e30f;
#pragma unroll
    for (int j = 0; j < 64; ++j) {
        float4 k0 = *(const float4*)(kb + (0 * 64 + j) * 4);
        float4 k1 = *(const float4*)(kb + (1 * 64 + j) * 4);
        float4 k2 = *(const float4*)(kb + (2 * 64 + j) * 4);
        float4 k3 = *(const float4*)(kb + (3 * 64 + j) * 4);
        float s0 = qd[0] * k0.x + qd[1] * k0.y + qd[2] * k0.z + qd[3] * k0.w;
        float s1 = qd[4] * k1.x + qd[5] * k1.y + qd[6] * k1.z + qd[7] * k1.w;
        float s2 = qd[8] * k2.x + qd[9] * k2.y + qd[10] * k2.z + qd[11] * k2.w;
        float s3 = qd[12] * k3.x + qd[13] * k3.y + qd[14] * k3.z + qd[15] * k3.w;
        float s = ((s0 + s1) + (s2 + s3)) * 0.25f;
        p[j] = s;
        if ((j & 3) == 0) m0 = fmaxf(m0, s);
        else if ((j & 3) == 1) m1 = fmaxf(m1, s);
        else if ((j & 3) == 2) m2 = fmaxf(m2, s);
        else m3 = fmaxf(m3, s);
    }
    const float m = fmaxf(fmaxf(m0, m1), fmaxf(m2, m3));
    float t0 = 0, t1 = 0, t2 = 0, t3 = 0;
#pragma unroll
    for (int j = 0; j < 64; j += 4) {
        p[j + 0] = __expf(p[j + 0] - m); t0 += p[j + 0];
        p[j + 1] = __expf(p[j + 1] - m); t1 += p[j + 1];
        p[j + 2] = __expf(p[j + 2] - m); t2 += p[j + 2];
        p[j + 3] = __expf(p[j + 3] - m); t3 += p[j + 3];
    }
    const float rs = 1.0f / ((t0 + t1) + (t2 + t3));

    // ---- phase 3: PV ----
    const float* vb = smem + ((8 + w) * 4) * 64 * 4;  // v section, head w
    float od[16];
#pragma unroll
    for (int d = 0; d < 16; ++d) od[d] = 0.f;
#pragma unroll
    for (int j = 0; j < 64; ++j) {
        const float pj = p[j];
        float4 v0 = *(const float4*)(vb + (0 * 64 + j) * 4);
        float4 v1 = *(const float4*)(vb + (1 * 64 + j) * 4);
        float4 v2 = *(const float4*)(vb + (2 * 64 + j) * 4);
        float4 v3 = *(const float4*)(vb + (3 * 64 + j) * 4);
        od[0] = fmaf(pj, v0.x, od[0]);  od[1] = fmaf(pj, v0.y, od[1]);
        od[2] = fmaf(pj, v0.z, od[2]);  od[3] = fmaf(pj, v0.w, od[3]);
        od[4] = fmaf(pj, v1.x, od[4]);  od[5] = fmaf(pj, v1.y, od[5]);
        od[6] = fmaf(pj, v1.z, od[6]);  od[7] = fmaf(pj, v1.w, od[7]);
        od[8] = fmaf(pj, v2.x, od[8]);  od[9] = fmaf(pj, v2.y, od[9]);
        od[10] = fmaf(pj, v2.z, od[10]); od[11] = fmaf(pj, v2.w, od[11]);
        od[12] = fmaf(pj, v3.x, od[12]); od[13] = fmaf(pj, v3.y, od[13]);
        od[14] = fmaf(pj, v3.z, od[14]); od[15] = fmaf(pj, v3.w, od[15]);
    }
    // write normalized O into head-w's q slot (sec = w)
#pragma unroll
    for (int d4 = 0; d4 < 4; ++d4)
        *(float4*)(smem + ((w * 4 + d4) * 64 + lane) * 4) =
            make_float4(od[4 * d4] * rs, od[4 * d4 + 1] * rs,
                        od[4 * d4 + 2] * rs, od[4 * d4 + 3] * rs);
    __syncthreads();

    // ---- phase 4: proj (wave w -> out ch [16w,16w+16)) ----
    float of[64];
#pragma unroll
    for (int h = 0; h < 4; ++h)
#pragma unroll
        for (int d4 = 0; d4 < 4; ++d4) {
            float4 v = *(const float4*)(smem + ((h * 4 + d4) * 64 + lane) * 4);
            of[h * 16 + 4 * d4 + 0] = v.x; of[h * 16 + 4 * d4 + 1] = v.y;
            of[h * 16 + 4 * d4 + 2] = v.z; of[h * 16 + 4 * d4 + 3] = v.w;
        }
    float outv[16];
#pragma unroll
    for (int ci = 0; ci < 16; ++ci) {
        const int c = w * 16 + ci;
        const float* wrow = projw + c * 64;
        float a0 = 0, a1 = 0, a2 = 0, a3 = 0;
#pragma unroll
        for (int d4 = 0; d4 < 16; ++d4) {
            float4 w4 = *(const float4*)(wrow + 4 * d4);
            a0 = fmaf(of[4 * d4 + 0], w4.x, a0);
            a1 = fmaf(of[4 * d4 + 1], w4.y, a1);
            a2 = fmaf(of[4 * d4 + 2], w4.z, a2);
            a3 = fmaf(of[4 * d4 + 3], w4.w, a3);
        }
        outv[ci] = (a0 + a1) + (a2 + a3) + projb[c];
    }
    float* dp = dst + (size_t)pix * 64 + w * 16;
#pragma unroll
    for (int q = 0; q < 4; ++q)
        *(float4*)(dp + 4 * q) = make_float4(outv[4 * q], outv[4 * q + 1],
                                             outv[4 * q + 2], outv[4 * q + 3]);
}

// ---------------------------------------------------------------------------
__global__ __launch_bounds__(256) void outconv_kernel(
    const float* __restrict__ h1, const float* __restrict__ ow,
    const float* __restrict__ ob, float* __restrict__ out)
{
    const int idx = blockIdx.x * 256 + threadIdx.x;
    const float* hp = h1 + (size_t)idx * 64;
    float a0 = 0, a1 = 0, a2 = 0, a3 = 0;
#pragma unroll
    for (int c4 = 0; c4 < 16; ++c4) {
        float4 h4 = *(const float4*)(hp + 4 * c4);
        float4 w4 = *(const float4*)(ow + 4 * c4);
        a0 = fmaf(h4.x, w4.x, a0);
        a1 = fmaf(h4.y, w4.y, a1);
        a2 = fmaf(h4.z, w4.z, a2);
        a3 = fmaf(h4.w, w4.w, a3);
    }
    out[idx] = (a0 + a1) + (a2 + a3) + ob[0];
}

// ---------------------------------------------------------------------------
extern "C" void kernel_launch(void* const* d_in, const int* in_sizes, int n_in,
                              void* d_out, int out_size, void* d_ws, size_t ws_size,
                              hipStream_t stream)
{
    const float* x      = (const float*)d_in[0];
    const float* cw0    = (const float*)d_in[1];
    const float* cb0    = (const float*)d_in[2];
    const float* pxw0   = (const float*)d_in[3];
    const float* pyw0   = (const float*)d_in[4];
    const float* qkvw0  = (const float*)d_in[5];
    const float* projw0 = (const float*)d_in[6];
    const float* projb0 = (const float*)d_in[7];
    const float* cw1    = (const float*)d_in[8];
    const float* cb1    = (const float*)d_in[9];
    const float* pxw1   = (const float*)d_in[10];
    const float* pyw1   = (const float*)d_in[11];
    const float* qkvw1  = (const float*)d_in[12];
    const float* projw1 = (const float*)d_in[13];
    const float* projb1 = (const float*)d_in[14];
    const float* outw   = (const float*)d_in[15];
    const float* outb   = (const float*)d_in[16];

    const size_t BUF = (size_t)16 * 128 * 128 * 64 * sizeof(float);  // 64 MB
    char* ws = (char*)d_ws;
    float* bufA = (float*)ws;                         // h2pre0 / h2pre1
    float* bufB = (float*)(ws + BUF);                 // h0 / h1
    unsigned short* pwb1 = (unsigned short*)(ws + 2 * BUF);   // [320][576] bf16
    float* pw0 = (float*)(ws + 2 * BUF + 400 * 1024);         // [5][9][64] fp32

    repack_kernel<<<(320 * 576 + 5 * 9 * 64 + 255) / 256, 256, 0, stream>>>(
        cw0, pxw0, pyw0, cw1, pxw1, pyw1, pwb1, pw0);

    gates1_kernel<<<16384, 256, 0, stream>>>(x, pw0, cb0, bufA);
    attn_kernel<<<4096, 256, 0, stream>>>(bufA, qkvw0, projw0, projb0, bufB);
    gates64_kernel<<<4096, 256, 0, stream>>>(bufB, pwb1, cb1, bufA);
    attn_kernel<<<4096, 256, 0, stream>>>(bufA, qkvw1, projw1, projb1, bufB);
    outconv_kernel<<<1024, 256, 0, stream>>>(bufB, outw, outb, (float*)d_out);
}

// Round 6
// 487.277 us; speedup vs baseline: 6.3811x; 1.5973x over previous
//
#include <hip/hip_runtime.h>

// ConvLSTM (B=16,H=128,W=128,CIN=1,HID=64, 2 cells, h=c=0 -> f-gate dead)
// Pipeline: repack -> gates1(fp32) -> attn(MFMA) -> gates64(MFMA) -> attn -> outconv

#define DEVFN __device__ __forceinline__

typedef __attribute__((ext_vector_type(8))) short short8;
typedef __attribute__((ext_vector_type(4))) float f32x4;

DEVFN float sigmoidf_(float z) { return 1.0f / (1.0f + __expf(-z)); }

DEVFN unsigned short f2bf(float f) {  // RNE fp32 -> bf16
    unsigned int u = __builtin_bit_cast(unsigned int, f);
    u += 0x7fffu + ((u >> 16) & 1u);
    return (unsigned short)(u >> 16);
}

DEVFN unsigned pkbf(float a, float b) {  // pack 2 fp32 -> 2 bf16 (RNE)
    return (unsigned)f2bf(a) | ((unsigned)f2bf(b) << 16);
}

// ---------------------------------------------------------------------------
// Repack: pwb1 bf16 [320][576]; pw0 fp32 [5][9][64]; qkv/proj weights -> bf16
// ---------------------------------------------------------------------------
__global__ __launch_bounds__(256) void repack_kernel(
    const float* __restrict__ cw0, const float* __restrict__ pxw0, const float* __restrict__ pyw0,
    const float* __restrict__ cw1, const float* __restrict__ pxw1, const float* __restrict__ pyw1,
    const float* __restrict__ qkvw0, const float* __restrict__ projw0,
    const float* __restrict__ qkvw1, const float* __restrict__ projw1,
    unsigned short* __restrict__ pwb1, float* __restrict__ pw0,
    unsigned short* __restrict__ qb0, unsigned short* __restrict__ pjb0,
    unsigned short* __restrict__ qb1, unsigned short* __restrict__ pjb1)
{
    int idx = blockIdx.x * 256 + threadIdx.x;
    if (idx < 320 * 576) {
        int n = idx / 576, k = idx - n * 576;
        int g = n >> 6, c = n & 63;
        int pos = k >> 6, cin = k & 63;
        float v;
        if (g == 0)      v = cw1[((c      ) * 128 + cin) * 9 + pos];  // ci
        else if (g == 1) v = cw1[((128 + c) * 128 + cin) * 9 + pos];  // co
        else if (g == 2) v = cw1[((192 + c) * 128 + cin) * 9 + pos];  // cg
        else if (g == 3) v = pxw1[(c * 64 + cin) * 9 + pos];          // px
        else             v = pyw1[(c * 64 + cin) * 9 + pos];          // py
        pwb1[idx] = f2bf(v);
    } else if (idx < 187200) {  // 320*576 + 5*9*64
        int i2 = idx - 320 * 576;
        int g = i2 / (9 * 64);
        int rem = i2 - g * (9 * 64);
        int pos = rem >> 6, c = rem & 63;
        float v;
        if (g == 0)      v = cw0[(c      ) * 585 + pos];
        else if (g == 1) v = cw0[(128 + c) * 585 + pos];
        else if (g == 2) v = cw0[(192 + c) * 585 + pos];
        else if (g == 3) v = pxw0[c * 9 + pos];
        else             v = pyw0[c * 9 + pos];
        pw0[i2] = v;
    } else if (idx < 187200 + 12288) {
        int i = idx - 187200;           qb0[i] = f2bf(qkvw0[i]);
    } else if (idx < 187200 + 24576) {
        int i = idx - 187200 - 12288;   qb1[i] = f2bf(qkvw1[i]);
    } else if (idx < 187200 + 24576 + 4096) {
        int i = idx - 187200 - 24576;   pjb0[i] = f2bf(projw0[i]);
    } else if (idx < 187200 + 24576 + 8192) {
        int i = idx - 187200 - 28672;   pjb1[i] = f2bf(projw1[i]);
    }
}

// ---------------------------------------------------------------------------
// Layer-0 gates (CIN=1): memory-bound.
// ---------------------------------------------------------------------------
__global__ __launch_bounds__(256) void gates1_kernel(
    const float* __restrict__ x, const float* __restrict__ pw,
    const float* __restrict__ cb, float* __restrict__ dst)
{
    const int idx = blockIdx.x * 256 + threadIdx.x;
    const int pix = idx >> 4, ch0 = (idx & 15) * 4;
    const int b = pix >> 14, y = (pix >> 7) & 127, xq = pix & 127;

    float a[9];
#pragma unroll
    for (int dy = 0; dy < 3; ++dy)
#pragma unroll
        for (int dx = 0; dx < 3; ++dx) {
            int gy = y + dy - 1, gx = xq + dx - 1;
            a[dy * 3 + dx] = ((unsigned)gy < 128u && (unsigned)gx < 128u)
                ? x[(b * 128 + gy) * 128 + gx] : 0.f;
        }

    float acc[5][4];
#pragma unroll
    for (int g = 0; g < 5; ++g)
#pragma unroll
        for (int u = 0; u < 4; ++u) acc[g][u] = 0.f;

#pragma unroll
    for (int pos = 0; pos < 9; ++pos) {
        const float av = a[pos];
#pragma unroll
        for (int g = 0; g < 5; ++g) {
            const float4 w4 = *(const float4*)(pw + (g * 9 + pos) * 64 + ch0);
            acc[g][0] = fmaf(av, w4.x, acc[g][0]);
            acc[g][1] = fmaf(av, w4.y, acc[g][1]);
            acc[g][2] = fmaf(av, w4.z, acc[g][2]);
            acc[g][3] = fmaf(av, w4.w, acc[g][3]);
        }
    }

    float hv[4];
#pragma unroll
    for (int u = 0; u < 4; ++u) {
        float ci = acc[0][u] + cb[ch0 + u];
        float co = acc[1][u] + cb[128 + ch0 + u];
        float cg = acc[2][u] + cb[192 + ch0 + u];
        float iv = sigmoidf_(ci + acc[3][u]);
        float ov = sigmoidf_(co + acc[4][u]);
        float gv = tanhf(cg + acc[4][u]);
        hv[u] = ov * tanhf(iv * gv);
    }
    *(float4*)(dst + (size_t)pix * 64 + ch0) = make_float4(hv[0], hv[1], hv[2], hv[3]);
}

// ---------------------------------------------------------------------------
// Layer-1 gates: bf16 MFMA implicit GEMM (verified round 2).
// ---------------------------------------------------------------------------
__global__ __launch_bounds__(256, 2) void gates64_kernel(
    const float* __restrict__ src, const unsigned short* __restrict__ wtb,
    const float* __restrict__ cb, float* __restrict__ dst)
{
    __shared__ unsigned short lds[3 * 66 * 64];
    char* const sbase = (char*)lds;

    const int tid = threadIdx.x;
    const int bid = blockIdx.x;
    const int xt = bid & 1, y = (bid >> 1) & 127, b = bid >> 8;
    const int x0 = xt * 64;

    for (int i4 = tid; i4 < 3 * 66 * 8; i4 += 256) {
        int r = i4 / (66 * 8);
        int rem = i4 - r * (66 * 8);
        int xx = rem >> 3, c8 = rem & 7;
        int gy = y + r - 1, gx = x0 + xx - 1;
        uint4 wv = make_uint4(0, 0, 0, 0);
        if ((unsigned)gy < 128u && (unsigned)gx < 128u) {
            const float* sp = src + (((size_t)(b * 128 + gy) * 128 + gx) * 64 + c8 * 8);
            float4 v0 = *(const float4*)(sp);
            float4 v1 = *(const float4*)(sp + 4);
            wv.x = pkbf(v0.x, v0.y); wv.y = pkbf(v0.z, v0.w);
            wv.z = pkbf(v1.x, v1.y); wv.w = pkbf(v1.z, v1.w);
        }
        int addr = ((r * 66 + xx) * 128 + c8 * 16) ^ ((xx & 7) << 4);
        *(uint4*)(sbase + addr) = wv;
    }
    __syncthreads();

    const int lane = tid & 63;
    const int wv_ = tid >> 6;
    const int r0 = lane & 15;
    const int hi = lane >> 4;
    const int wch = wv_ * 16 + r0;

    const unsigned short* bp[5];
#pragma unroll
    for (int g = 0; g < 5; ++g)
        bp[g] = wtb + (size_t)(g * 64 + wch) * 576 + hi * 8;

    f32x4 acc[4][5];
#pragma unroll
    for (int mt = 0; mt < 4; ++mt)
#pragma unroll
        for (int g = 0; g < 5; ++g) acc[mt][g] = (f32x4){0.f, 0.f, 0.f, 0.f};

#pragma unroll
    for (int kk = 0; kk < 18; ++kk) {
        const int pos = kk >> 1, dy = pos / 3, dx = pos % 3, chalf = kk & 1;
        const int swz = (((r0 + dx) & 7) << 4);
        short8 afr[4];
#pragma unroll
        for (int mt = 0; mt < 4; ++mt) {
            const int row = dy * 66 + mt * 16 + r0 + dx;
            const int addr = (row * 128 + chalf * 64 + hi * 16) ^ swz;
            afr[mt] = *(const short8*)(sbase + addr);
        }
        short8 bfr[5];
#pragma unroll
        for (int g = 0; g < 5; ++g)
            bfr[g] = *(const short8*)(bp[g] + kk * 32);
#pragma unroll
        for (int mt = 0; mt < 4; ++mt)
#pragma unroll
            for (int g = 0; g < 5; ++g)
                acc[mt][g] = __builtin_amdgcn_mfma_f32_16x16x32_bf16(
                    afr[mt], bfr[g], acc[mt][g], 0, 0, 0);
    }

    const float bci = cb[wch], bco = cb[128 + wch], bcg = cb[192 + wch];
    const int rowbase = (b * 128 + y) * 128 + x0;
#pragma unroll
    for (int mt = 0; mt < 4; ++mt) {
#pragma unroll
        for (int rg = 0; rg < 4; ++rg) {
            const int px_i = mt * 16 + hi * 4 + rg;
            float ci = acc[mt][0][rg] + bci;
            float co = acc[mt][1][rg] + bco;
            float cg = acc[mt][2][rg] + bcg;
            float pxv = acc[mt][3][rg];
            float pyv = acc[mt][4][rg];
            float iv = sigmoidf_(ci + pxv);
            float ov = sigmoidf_(co + pyv);
            float gv = tanhf(cg + pyv);
            dst[(size_t)(rowbase + px_i) * 64 + wch] = ov * tanhf(iv * gv);
        }
    }
}

// ---------------------------------------------------------------------------
// Window attention v3: full bf16 MFMA. One 8x8 window per 256-thread block.
// Heads processed sequentially; all 4 waves cooperate per head.
// ---------------------------------------------------------------------------
__global__ __launch_bounds__(256, 4) void attn_kernel(
    const float* __restrict__ src,             // NHWC [16,128,128,64] fp32
    const unsigned short* __restrict__ qkvwb,  // [192][64] bf16
    const unsigned short* __restrict__ projwb, // [64][64] bf16
    const float* __restrict__ projb,           // [64]
    float* __restrict__ dst)                   // NHWC fp32
{
    __shared__ char sm[32768];
    char* const Xs = sm;            // [64 tok][128B] swz ((tok&7)<<4)
    char* const Xo = sm + 8192;     // [64 tok][128B] swz ((tok&7)<<4)
    char* const Qs = sm + 16384;    // [64 tok][48B]  (24 bf16 slots, 16 used)
    char* const Ks = sm + 19456;    // [64 tok][48B]
    char* const VT = sm + 22528;    // [16 d][128B]   swz ((d&7)<<4)
    char* const Ps = sm + 24576;    // [64 q][128B]   swz ((q&7)<<4)

    const int tid = threadIdx.x;
    const int lane = tid & 63;
    const int w = __builtin_amdgcn_readfirstlane(tid >> 6);
    const int lo = lane & 15, hi = lane >> 4;
    const int wid = blockIdx.x;
    const int b = wid >> 8, rem = wid & 255, wy = rem >> 4, wx = rem & 15;
    const int pixbase = (b * 128 + wy * 8) * 128 + wx * 8;

    // ---- stage X: fp32 -> bf16 swizzled; thread = (token, 16-ch group) ----
    {
        const int t = tid >> 2, c0 = (tid & 3) * 16;
        const int pix = pixbase + (t >> 3) * 128 + (t & 7);
        const float* sp = src + (size_t)pix * 64 + c0;
        float4 v0 = *(const float4*)(sp + 0);
        float4 v1 = *(const float4*)(sp + 4);
        float4 v2 = *(const float4*)(sp + 8);
        float4 v3 = *(const float4*)(sp + 12);
        uint4 w0, w1;
        w0.x = pkbf(v0.x, v0.y); w0.y = pkbf(v0.z, v0.w);
        w0.z = pkbf(v1.x, v1.y); w0.w = pkbf(v1.z, v1.w);
        w1.x = pkbf(v2.x, v2.y); w1.y = pkbf(v2.z, v2.w);
        w1.z = pkbf(v3.x, v3.y); w1.w = pkbf(v3.z, v3.w);
        const int a = t * 128 + c0 * 2, sz = (t & 7) << 4;
        *(uint4*)(Xs + (a ^ sz)) = w0;
        *(uint4*)(Xs + ((a + 16) ^ sz)) = w1;
    }
    __syncthreads();

    const int trow = w * 16 + lo;          // this lane's token/q row
    const int tswz = (lo & 7) << 4;        // == (trow&7)<<4

    for (int h = 0; h < 4; ++h) {
        // ---- qkv for head h (6 MFMA) ----
        f32x4 cq = {0.f, 0.f, 0.f, 0.f}, ck = cq, cv = cq;
#pragma unroll
        for (int ks = 0; ks < 2; ++ks) {
            const int koff = hi * 8 + ks * 32;  // cin
            short8 xb = *(const short8*)(Xs + ((trow * 128 + koff * 2) ^ tswz));
            short8 aq = *(const short8*)(qkvwb + (h * 16 + lo) * 64 + koff);
            short8 ak = *(const short8*)(qkvwb + (64 + h * 16 + lo) * 64 + koff);
            short8 bv = *(const short8*)(qkvwb + (128 + h * 16 + lo) * 64 + koff);
            cq = __builtin_amdgcn_mfma_f32_16x16x32_bf16(aq, xb, cq, 0, 0, 0);
            ck = __builtin_amdgcn_mfma_f32_16x16x32_bf16(ak, xb, ck, 0, 0, 0);
            cv = __builtin_amdgcn_mfma_f32_16x16x32_bf16(xb, bv, cv, 0, 0, 0);
        }
        {   // Q^T/K^T C: [d'=hi*4+r][tok=trow] -> Qs/Ks[tok][d'] contiguous
            uint2 qw, kw, vw;
            qw.x = pkbf(cq[0] * 0.125f, cq[1] * 0.125f);
            qw.y = pkbf(cq[2] * 0.125f, cq[3] * 0.125f);
            kw.x = pkbf(ck[0], ck[1]); kw.y = pkbf(ck[2], ck[3]);
            *(uint2*)(Qs + trow * 48 + hi * 8) = qw;
            *(uint2*)(Ks + trow * 48 + hi * 8) = kw;
            // V C: [tok=w*16+hi*4+r][d'=lo] -> VT[d'=lo][tok] contiguous
            vw.x = pkbf(cv[0], cv[1]); vw.y = pkbf(cv[2], cv[3]);
            *(uint2*)(VT + ((lo * 128 + (w * 16 + hi * 4) * 2) ^ ((lo & 7) << 4))) = vw;
        }
        __syncthreads();  // barrier A: Q/K/VT complete

        // ---- scores: S^T tiles (mt 0..3, nt=w); duplicated k-halves ----
        short8 bq = *(const short8*)(Qs + trow * 48 + (hi & 1) * 16);
        f32x4 st[4];
#pragma unroll
        for (int mt = 0; mt < 4; ++mt) {
            short8 ak2 = *(const short8*)(Ks + (mt * 16 + lo) * 48 + (hi & 1) * 16);
            f32x4 z = {0.f, 0.f, 0.f, 0.f};
            st[mt] = __builtin_amdgcn_mfma_f32_16x16x32_bf16(ak2, bq, z, 0, 0, 0);
        }
        // softmax over keys: 16 in-reg + hi-groups via xor 16,32
        float mx = -1e30f;
#pragma unroll
        for (int mt = 0; mt < 4; ++mt)
#pragma unroll
            for (int r = 0; r < 4; ++r) mx = fmaxf(mx, st[mt][r]);
        mx = fmaxf(mx, __shfl_xor(mx, 16));
        mx = fmaxf(mx, __shfl_xor(mx, 32));
        float pv[16];
        float sum = 0.f;
#pragma unroll
        for (int mt = 0; mt < 4; ++mt)
#pragma unroll
            for (int r = 0; r < 4; ++r) {
                float e = __expf(st[mt][r] - mx);
                pv[mt * 4 + r] = e;
                sum += e;
            }
        sum += __shfl_xor(sum, 16);
        sum += __shfl_xor(sum, 32);
        const float rs = 1.0f / sum;
#pragma unroll
        for (int mt = 0; mt < 4; ++mt) {
            uint2 pw_;
            pw_.x = pkbf(pv[mt * 4 + 0] * rs, pv[mt * 4 + 1] * rs);
            pw_.y = pkbf(pv[mt * 4 + 2] * rs, pv[mt * 4 + 3] * rs);
            *(uint2*)(Ps + ((trow * 128 + (mt * 16 + hi * 4) * 2) ^ tswz)) = pw_;
        }
        // no barrier: PV reads only this wave's P rows (+ VT covered by A)

        // ---- PV: O^T = V^T · P^T (2 MFMA) ----
        f32x4 ot = {0.f, 0.f, 0.f, 0.f};
#pragma unroll
        for (int ks = 0; ks < 2; ++ks) {
            const int ko = (hi * 8 + ks * 32) * 2;
            short8 av = *(const short8*)(VT + ((lo * 128 + ko) ^ ((lo & 7) << 4)));
            short8 bp = *(const short8*)(Ps + ((trow * 128 + ko) ^ tswz));
            ot = __builtin_amdgcn_mfma_f32_16x16x32_bf16(av, bp, ot, 0, 0, 0);
        }
        // O^T C: [d'=hi*4+r][q=trow] -> Xo[q][h*16+d'] contiguous
        {
            uint2 ow_;
            ow_.x = pkbf(ot[0], ot[1]); ow_.y = pkbf(ot[2], ot[3]);
            *(uint2*)(Xo + ((trow * 128 + (h * 16 + hi * 4) * 2) ^ tswz)) = ow_;
        }
        __syncthreads();  // barrier B: reads done; next head may rewrite
    }

    // ---- proj: Y tiles (mt 0..3, nt=w), K=64 ----
    f32x4 cy[4];
#pragma unroll
    for (int mt = 0; mt < 4; ++mt) cy[mt] = (f32x4){0.f, 0.f, 0.f, 0.f};
#pragma unroll
    for (int ks = 0; ks < 2; ++ks) {
        const int koff = hi * 8 + ks * 32;
        short8 bw = *(const short8*)(projwb + (w * 16 + lo) * 64 + koff);
#pragma unroll
        for (int mt = 0; mt < 4; ++mt) {
            short8 ax = *(const short8*)(Xo + (((mt * 16 + lo) * 128 + koff * 2) ^ ((lo & 7) << 4)));
            cy[mt] = __builtin_amdgcn_mfma_f32_16x16x32_bf16(ax, bw, cy[mt], 0, 0, 0);
        }
    }
    const float pb = projb[w * 16 + lo];
#pragma unroll
    for (int mt = 0; mt < 4; ++mt) {
#pragma unroll
        for (int r = 0; r < 4; ++r) {
            const int tok = mt * 16 + hi * 4 + r;
            const int pix = pixbase + (tok >> 3) * 128 + (tok & 7);
            dst[(size_t)pix * 64 + w * 16 + lo] = cy[mt][r] + pb;
        }
    }
}

// ---------------------------------------------------------------------------
__global__ __launch_bounds__(256) void outconv_kernel(
    const float* __restrict__ h1, const float* __restrict__ ow,
    const float* __restrict__ ob, float* __restrict__ out)
{
    const int idx = blockIdx.x * 256 + threadIdx.x;
    const float* hp = h1 + (size_t)idx * 64;
    float a0 = 0, a1 = 0, a2 = 0, a3 = 0;
#pragma unroll
    for (int c4 = 0; c4 < 16; ++c4) {
        float4 h4 = *(const float4*)(hp + 4 * c4);
        float4 w4 = *(const float4*)(ow + 4 * c4);
        a0 = fmaf(h4.x, w4.x, a0);
        a1 = fmaf(h4.y, w4.y, a1);
        a2 = fmaf(h4.z, w4.z, a2);
        a3 = fmaf(h4.w, w4.w, a3);
    }
    out[idx] = (a0 + a1) + (a2 + a3) + ob[0];
}

// ---------------------------------------------------------------------------
extern "C" void kernel_launch(void* const* d_in, const int* in_sizes, int n_in,
                              void* d_out, int out_size, void* d_ws, size_t ws_size,
                              hipStream_t stream)
{
    const float* x      = (const float*)d_in[0];
    const float* cw0    = (const float*)d_in[1];
    const float* cb0    = (const float*)d_in[2];
    const float* pxw0   = (const float*)d_in[3];
    const float* pyw0   = (const float*)d_in[4];
    const float* qkvw0  = (const float*)d_in[5];
    const float* projw0 = (const float*)d_in[6];
    const float* projb0 = (const float*)d_in[7];
    const float* cw1    = (const float*)d_in[8];
    const float* cb1    = (const float*)d_in[9];
    const float* pxw1   = (const float*)d_in[10];
    const float* pyw1   = (const float*)d_in[11];
    const float* qkvw1  = (const float*)d_in[12];
    const float* projw1 = (const float*)d_in[13];
    const float* projb1 = (const float*)d_in[14];
    const float* outw   = (const float*)d_in[15];
    const float* outb   = (const float*)d_in[16];

    const size_t BUF = (size_t)16 * 128 * 128 * 64 * sizeof(float);  // 64 MB
    char* ws = (char*)d_ws;
    float* bufA = (float*)ws;
    float* bufB = (float*)(ws + BUF);
    char* wsx = ws + 2 * BUF;
    // FIXED layout (round-5 bug: pw0 needs 2880 floats = 11520 B, had 9216):
    unsigned short* pwb1 = (unsigned short*)(wsx);            // [0,      368640)
    float* pw0           = (float*)(wsx + 369664);            // [369664, 381184)
    unsigned short* qb0  = (unsigned short*)(wsx + 381440);   // [381440, 406016)
    unsigned short* pjb0 = (unsigned short*)(wsx + 406016);   // [406016, 414208)
    unsigned short* qb1  = (unsigned short*)(wsx + 414208);   // [414208, 438784)
    unsigned short* pjb1 = (unsigned short*)(wsx + 438784);   // [438784, 446976)

    repack_kernel<<<860, 256, 0, stream>>>(
        cw0, pxw0, pyw0, cw1, pxw1, pyw1,
        qkvw0, projw0, qkvw1, projw1,
        pwb1, pw0, qb0, pjb0, qb1, pjb1);

    gates1_kernel<<<16384, 256, 0, stream>>>(x, pw0, cb0, bufA);
    attn_kernel<<<4096, 256, 0, stream>>>(bufA, qb0, pjb0, projb0, bufB);
    gates64_kernel<<<4096, 256, 0, stream>>>(bufB, pwb1, cb1, bufA);
    attn_kernel<<<4096, 256, 0, stream>>>(bufA, qb1, pjb1, projb1, bufB);
    outconv_kernel<<<1024, 256, 0, stream>>>(bufB, outw, outb, (float*)d_out);
}

// Round 7
// 463.173 us; speedup vs baseline: 6.7132x; 1.0520x over previous
//
#include <hip/hip_runtime.h>

// ConvLSTM (B=16,H=128,W=128,CIN=1,HID=64, 2 cells, h=c=0 -> f-gate dead)
// Round 7: all intermediates bf16 (bit-identical: consumers rounded to bf16
// anyway); outconv fused into attn1 epilogue (h1 never hits HBM).
// Pipeline: repack -> gates1 -> attn<0> -> gates64 -> attn<1>(+outconv)

#define DEVFN __device__ __forceinline__

typedef __attribute__((ext_vector_type(8))) short short8;
typedef __attribute__((ext_vector_type(4))) float f32x4;

DEVFN float sigmoidf_(float z) { return 1.0f / (1.0f + __expf(-z)); }

DEVFN unsigned short f2bf(float f) {  // RNE fp32 -> bf16
    unsigned int u = __builtin_bit_cast(unsigned int, f);
    u += 0x7fffu + ((u >> 16) & 1u);
    return (unsigned short)(u >> 16);
}

DEVFN unsigned pkbf(float a, float b) {  // pack 2 fp32 -> 2 bf16 (RNE)
    return (unsigned)f2bf(a) | ((unsigned)f2bf(b) << 16);
}

// ---------------------------------------------------------------------------
// Repack: pwb1 bf16 [320][576]; pw0 fp32 [5][9][64]; qkv/proj weights -> bf16
// ---------------------------------------------------------------------------
__global__ __launch_bounds__(256) void repack_kernel(
    const float* __restrict__ cw0, const float* __restrict__ pxw0, const float* __restrict__ pyw0,
    const float* __restrict__ cw1, const float* __restrict__ pxw1, const float* __restrict__ pyw1,
    const float* __restrict__ qkvw0, const float* __restrict__ projw0,
    const float* __restrict__ qkvw1, const float* __restrict__ projw1,
    unsigned short* __restrict__ pwb1, float* __restrict__ pw0,
    unsigned short* __restrict__ qb0, unsigned short* __restrict__ pjb0,
    unsigned short* __restrict__ qb1, unsigned short* __restrict__ pjb1)
{
    int idx = blockIdx.x * 256 + threadIdx.x;
    if (idx < 320 * 576) {
        int n = idx / 576, k = idx - n * 576;
        int g = n >> 6, c = n & 63;
        int pos = k >> 6, cin = k & 63;
        float v;
        if (g == 0)      v = cw1[((c      ) * 128 + cin) * 9 + pos];  // ci
        else if (g == 1) v = cw1[((128 + c) * 128 + cin) * 9 + pos];  // co
        else if (g == 2) v = cw1[((192 + c) * 128 + cin) * 9 + pos];  // cg
        else if (g == 3) v = pxw1[(c * 64 + cin) * 9 + pos];          // px
        else             v = pyw1[(c * 64 + cin) * 9 + pos];          // py
        pwb1[idx] = f2bf(v);
    } else if (idx < 187200) {  // 320*576 + 5*9*64
        int i2 = idx - 320 * 576;
        int g = i2 / (9 * 64);
        int rem = i2 - g * (9 * 64);
        int pos = rem >> 6, c = rem & 63;
        float v;
        if (g == 0)      v = cw0[(c      ) * 585 + pos];
        else if (g == 1) v = cw0[(128 + c) * 585 + pos];
        else if (g == 2) v = cw0[(192 + c) * 585 + pos];
        else if (g == 3) v = pxw0[c * 9 + pos];
        else             v = pyw0[c * 9 + pos];
        pw0[i2] = v;
    } else if (idx < 187200 + 12288) {
        int i = idx - 187200;           qb0[i] = f2bf(qkvw0[i]);
    } else if (idx < 187200 + 24576) {
        int i = idx - 187200 - 12288;   qb1[i] = f2bf(qkvw1[i]);
    } else if (idx < 187200 + 24576 + 4096) {
        int i = idx - 187200 - 24576;   pjb0[i] = f2bf(projw0[i]);
    } else if (idx < 187200 + 24576 + 8192) {
        int i = idx - 187200 - 28672;   pjb1[i] = f2bf(projw1[i]);
    }
}

// ---------------------------------------------------------------------------
// Layer-0 gates (CIN=1): memory-bound; bf16 output.
// ---------------------------------------------------------------------------
__global__ __launch_bounds__(256) void gates1_kernel(
    const float* __restrict__ x, const float* __restrict__ pw,
    const float* __restrict__ cb, unsigned short* __restrict__ dst)
{
    const int idx = blockIdx.x * 256 + threadIdx.x;
    const int pix = idx >> 4, ch0 = (idx & 15) * 4;
    const int b = pix >> 14, y = (pix >> 7) & 127, xq = pix & 127;

    float a[9];
#pragma unroll
    for (int dy = 0; dy < 3; ++dy)
#pragma unroll
        for (int dx = 0; dx < 3; ++dx) {
            int gy = y + dy - 1, gx = xq + dx - 1;
            a[dy * 3 + dx] = ((unsigned)gy < 128u && (unsigned)gx < 128u)
                ? x[(b * 128 + gy) * 128 + gx] : 0.f;
        }

    float acc[5][4];
#pragma unroll
    for (int g = 0; g < 5; ++g)
#pragma unroll
        for (int u = 0; u < 4; ++u) acc[g][u] = 0.f;

#pragma unroll
    for (int pos = 0; pos < 9; ++pos) {
        const float av = a[pos];
#pragma unroll
        for (int g = 0; g < 5; ++g) {
            const float4 w4 = *(const float4*)(pw + (g * 9 + pos) * 64 + ch0);
            acc[g][0] = fmaf(av, w4.x, acc[g][0]);
            acc[g][1] = fmaf(av, w4.y, acc[g][1]);
            acc[g][2] = fmaf(av, w4.z, acc[g][2]);
            acc[g][3] = fmaf(av, w4.w, acc[g][3]);
        }
    }

    float hv[4];
#pragma unroll
    for (int u = 0; u < 4; ++u) {
        float ci = acc[0][u] + cb[ch0 + u];
        float co = acc[1][u] + cb[128 + ch0 + u];
        float cg = acc[2][u] + cb[192 + ch0 + u];
        float iv = sigmoidf_(ci + acc[3][u]);
        float ov = sigmoidf_(co + acc[4][u]);
        float gv = tanhf(cg + acc[4][u]);
        hv[u] = ov * tanhf(iv * gv);
    }
    uint2 o;
    o.x = pkbf(hv[0], hv[1]);
    o.y = pkbf(hv[2], hv[3]);
    *(uint2*)(dst + (size_t)pix * 64 + ch0) = o;
}

// ---------------------------------------------------------------------------
// Layer-1 gates: bf16 MFMA implicit GEMM. bf16 in, bf16 out.
// ---------------------------------------------------------------------------
__global__ __launch_bounds__(256, 2) void gates64_kernel(
    const unsigned short* __restrict__ src, const unsigned short* __restrict__ wtb,
    const float* __restrict__ cb, unsigned short* __restrict__ dst)
{
    __shared__ unsigned short lds[3 * 66 * 64];
    char* const sbase = (char*)lds;

    const int tid = threadIdx.x;
    const int bid = blockIdx.x;
    const int xt = bid & 1, y = (bid >> 1) & 127, b = bid >> 8;
    const int x0 = xt * 64;

    // stage A: bf16 copy, swizzled
    for (int i4 = tid; i4 < 3 * 66 * 8; i4 += 256) {
        int r = i4 / (66 * 8);
        int rem = i4 - r * (66 * 8);
        int xx = rem >> 3, c8 = rem & 7;
        int gy = y + r - 1, gx = x0 + xx - 1;
        uint4 wv = make_uint4(0, 0, 0, 0);
        if ((unsigned)gy < 128u && (unsigned)gx < 128u)
            wv = *(const uint4*)(src + (((size_t)(b * 128 + gy) * 128 + gx) * 64 + c8 * 8));
        int addr = ((r * 66 + xx) * 128 + c8 * 16) ^ ((xx & 7) << 4);
        *(uint4*)(sbase + addr) = wv;
    }
    __syncthreads();

    const int lane = tid & 63;
    const int wv_ = tid >> 6;
    const int r0 = lane & 15;
    const int hi = lane >> 4;
    const int wch = wv_ * 16 + r0;

    const unsigned short* bp[5];
#pragma unroll
    for (int g = 0; g < 5; ++g)
        bp[g] = wtb + (size_t)(g * 64 + wch) * 576 + hi * 8;

    f32x4 acc[4][5];
#pragma unroll
    for (int mt = 0; mt < 4; ++mt)
#pragma unroll
        for (int g = 0; g < 5; ++g) acc[mt][g] = (f32x4){0.f, 0.f, 0.f, 0.f};

#pragma unroll
    for (int kk = 0; kk < 18; ++kk) {
        const int pos = kk >> 1, dy = pos / 3, dx = pos % 3, chalf = kk & 1;
        const int swz = (((r0 + dx) & 7) << 4);
        short8 bfr[5];
#pragma unroll
        for (int g = 0; g < 5; ++g)
            bfr[g] = *(const short8*)(bp[g] + kk * 32);
        short8 afr[4];
#pragma unroll
        for (int mt = 0; mt < 4; ++mt) {
            const int row = dy * 66 + mt * 16 + r0 + dx;
            const int addr = (row * 128 + chalf * 64 + hi * 16) ^ swz;
            afr[mt] = *(const short8*)(sbase + addr);
        }
#pragma unroll
        for (int mt = 0; mt < 4; ++mt)
#pragma unroll
            for (int g = 0; g < 5; ++g)
                acc[mt][g] = __builtin_amdgcn_mfma_f32_16x16x32_bf16(
                    afr[mt], bfr[g], acc[mt][g], 0, 0, 0);
    }

    const float bci = cb[wch], bco = cb[128 + wch], bcg = cb[192 + wch];
    const int rowbase = (b * 128 + y) * 128 + x0;
#pragma unroll
    for (int mt = 0; mt < 4; ++mt) {
#pragma unroll
        for (int rg = 0; rg < 4; ++rg) {
            const int px_i = mt * 16 + hi * 4 + rg;
            float ci = acc[mt][0][rg] + bci;
            float co = acc[mt][1][rg] + bco;
            float cg = acc[mt][2][rg] + bcg;
            float pxv = acc[mt][3][rg];
            float pyv = acc[mt][4][rg];
            float iv = sigmoidf_(ci + pxv);
            float ov = sigmoidf_(co + pyv);
            float gv = tanhf(cg + pyv);
            dst[(size_t)(rowbase + px_i) * 64 + wch] = f2bf(ov * tanhf(iv * gv));
        }
    }
}

// ---------------------------------------------------------------------------
// Window attention (full bf16 MFMA). FUSE=1: fold 1x1 outconv into epilogue
// (skip h1 store entirely; fp32 channel-dot via shfl + LDS cross-wave add).
// ---------------------------------------------------------------------------
template <int FUSE>
__global__ __launch_bounds__(256, 4) void attn_kernel(
    const unsigned short* __restrict__ src,    // NHWC bf16 [16,128,128,64]
    const unsigned short* __restrict__ qkvwb,  // [192][64] bf16
    const unsigned short* __restrict__ projwb, // [64][64] bf16
    const float* __restrict__ projb,           // [64]
    unsigned short* __restrict__ dst,          // NHWC bf16 (FUSE=0)
    const float* __restrict__ outw,            // [64] (FUSE=1)
    const float* __restrict__ outb,            // [1]  (FUSE=1)
    float* __restrict__ out)                   // [16,128,128,1] (FUSE=1)
{
    __shared__ char sm[32768];
    char* const Xs = sm;            // [64 tok][128B] swz ((tok&7)<<4)
    char* const Xo = sm + 8192;     // [64 tok][128B] swz ((tok&7)<<4)
    char* const Qs = sm + 16384;    // [64 tok][48B]
    char* const Ks = sm + 19456;    // [64 tok][48B]
    char* const VT = sm + 22528;    // [16 d][128B] swz; reused as red[64][4] f32
    char* const Ps = sm + 24576;    // [64 q][128B] swz

    const int tid = threadIdx.x;
    const int lane = tid & 63;
    const int w = __builtin_amdgcn_readfirstlane(tid >> 6);
    const int lo = lane & 15, hi = lane >> 4;
    const int wid = blockIdx.x;
    const int b = wid >> 8, rem = wid & 255, wy = rem >> 4, wx = rem & 15;
    const int pixbase = (b * 128 + wy * 8) * 128 + wx * 8;

    // ---- stage X: bf16 copy, swizzled ----
    {
        const int t = tid >> 2, c0 = (tid & 3) * 16;
        const int pix = pixbase + (t >> 3) * 128 + (t & 7);
        const uint4* sp = (const uint4*)(src + (size_t)pix * 64 + c0);
        uint4 w0 = sp[0], w1 = sp[1];
        const int a = t * 128 + c0 * 2, sz = (t & 7) << 4;
        *(uint4*)(Xs + (a ^ sz)) = w0;
        *(uint4*)(Xs + ((a + 16) ^ sz)) = w1;
    }
    __syncthreads();

    const int trow = w * 16 + lo;
    const int tswz = (lo & 7) << 4;

    for (int h = 0; h < 4; ++h) {
        // ---- qkv for head h ----
        f32x4 cq = {0.f, 0.f, 0.f, 0.f}, ck = cq, cv = cq;
#pragma unroll
        for (int ks = 0; ks < 2; ++ks) {
            const int koff = hi * 8 + ks * 32;
            short8 xb = *(const short8*)(Xs + ((trow * 128 + koff * 2) ^ tswz));
            short8 aq = *(const short8*)(qkvwb + (h * 16 + lo) * 64 + koff);
            short8 ak = *(const short8*)(qkvwb + (64 + h * 16 + lo) * 64 + koff);
            short8 bv = *(const short8*)(qkvwb + (128 + h * 16 + lo) * 64 + koff);
            cq = __builtin_amdgcn_mfma_f32_16x16x32_bf16(aq, xb, cq, 0, 0, 0);
            ck = __builtin_amdgcn_mfma_f32_16x16x32_bf16(ak, xb, ck, 0, 0, 0);
            cv = __builtin_amdgcn_mfma_f32_16x16x32_bf16(xb, bv, cv, 0, 0, 0);
        }
        {
            uint2 qw, kw, vw;
            qw.x = pkbf(cq[0] * 0.125f, cq[1] * 0.125f);
            qw.y = pkbf(cq[2] * 0.125f, cq[3] * 0.125f);
            kw.x = pkbf(ck[0], ck[1]); kw.y = pkbf(ck[2], ck[3]);
            *(uint2*)(Qs + trow * 48 + hi * 8) = qw;
            *(uint2*)(Ks + trow * 48 + hi * 8) = kw;
            vw.x = pkbf(cv[0], cv[1]); vw.y = pkbf(cv[2], cv[3]);
            *(uint2*)(VT + ((lo * 128 + (w * 16 + hi * 4) * 2) ^ ((lo & 7) << 4))) = vw;
        }
        __syncthreads();  // barrier A

        // ---- scores (duplicated k-halves; Q pre-scaled 0.125) ----
        short8 bq = *(const short8*)(Qs + trow * 48 + (hi & 1) * 16);
        f32x4 st[4];
#pragma unroll
        for (int mt = 0; mt < 4; ++mt) {
            short8 ak2 = *(const short8*)(Ks + (mt * 16 + lo) * 48 + (hi & 1) * 16);
            f32x4 z = {0.f, 0.f, 0.f, 0.f};
            st[mt] = __builtin_amdgcn_mfma_f32_16x16x32_bf16(ak2, bq, z, 0, 0, 0);
        }
        float mx = -1e30f;
#pragma unroll
        for (int mt = 0; mt < 4; ++mt)
#pragma unroll
            for (int r = 0; r < 4; ++r) mx = fmaxf(mx, st[mt][r]);
        mx = fmaxf(mx, __shfl_xor(mx, 16));
        mx = fmaxf(mx, __shfl_xor(mx, 32));
        float pv[16];
        float sum = 0.f;
#pragma unroll
        for (int mt = 0; mt < 4; ++mt)
#pragma unroll
            for (int r = 0; r < 4; ++r) {
                float e = __expf(st[mt][r] - mx);
                pv[mt * 4 + r] = e;
                sum += e;
            }
        sum += __shfl_xor(sum, 16);
        sum += __shfl_xor(sum, 32);
        const float rs = 1.0f / sum;
#pragma unroll
        for (int mt = 0; mt < 4; ++mt) {
            uint2 pw_;
            pw_.x = pkbf(pv[mt * 4 + 0] * rs, pv[mt * 4 + 1] * rs);
            pw_.y = pkbf(pv[mt * 4 + 2] * rs, pv[mt * 4 + 3] * rs);
            *(uint2*)(Ps + ((trow * 128 + (mt * 16 + hi * 4) * 2) ^ tswz)) = pw_;
        }

        // ---- PV: O^T = V^T · P^T ----
        f32x4 ot = {0.f, 0.f, 0.f, 0.f};
#pragma unroll
        for (int ks = 0; ks < 2; ++ks) {
            const int ko = (hi * 8 + ks * 32) * 2;
            short8 av = *(const short8*)(VT + ((lo * 128 + ko) ^ ((lo & 7) << 4)));
            short8 bp = *(const short8*)(Ps + ((trow * 128 + ko) ^ tswz));
            ot = __builtin_amdgcn_mfma_f32_16x16x32_bf16(av, bp, ot, 0, 0, 0);
        }
        {
            uint2 ow_;
            ow_.x = pkbf(ot[0], ot[1]); ow_.y = pkbf(ot[2], ot[3]);
            *(uint2*)(Xo + ((trow * 128 + (h * 16 + hi * 4) * 2) ^ tswz)) = ow_;
        }
        __syncthreads();  // barrier B
    }

    // ---- proj ----
    f32x4 cy[4];
#pragma unroll
    for (int mt = 0; mt < 4; ++mt) cy[mt] = (f32x4){0.f, 0.f, 0.f, 0.f};
#pragma unroll
    for (int ks = 0; ks < 2; ++ks) {
        const int koff = hi * 8 + ks * 32;
        short8 bw = *(const short8*)(projwb + (w * 16 + lo) * 64 + koff);
#pragma unroll
        for (int mt = 0; mt < 4; ++mt) {
            short8 ax = *(const short8*)(Xo + (((mt * 16 + lo) * 128 + koff * 2) ^ ((lo & 7) << 4)));
            cy[mt] = __builtin_amdgcn_mfma_f32_16x16x32_bf16(ax, bw, cy[mt], 0, 0, 0);
        }
    }
    const float pb = projb[w * 16 + lo];

    if constexpr (FUSE == 0) {
#pragma unroll
        for (int mt = 0; mt < 4; ++mt) {
#pragma unroll
            for (int r = 0; r < 4; ++r) {
                const int tok = mt * 16 + hi * 4 + r;
                const int pix = pixbase + (tok >> 3) * 128 + (tok & 7);
                dst[(size_t)pix * 64 + w * 16 + lo] = f2bf(cy[mt][r] + pb);
            }
        }
    } else {
        // fused 1x1 outconv: out[tok] = sum_ch (Y[tok][ch]) * ow[ch] + ob
        const float owv = outw[w * 16 + lo];
        float* red = (float*)VT;  // [64 tok][4 waves]
#pragma unroll
        for (int mt = 0; mt < 4; ++mt) {
#pragma unroll
            for (int r = 0; r < 4; ++r) {
                float s = (cy[mt][r] + pb) * owv;
                s += __shfl_xor(s, 1);
                s += __shfl_xor(s, 2);
                s += __shfl_xor(s, 4);
                s += __shfl_xor(s, 8);
                if (lo == 0) red[(mt * 16 + hi * 4 + r) * 4 + w] = s;
            }
        }
        __syncthreads();
        if (tid < 64) {
            const int tok = tid;
            float4 rv = *(const float4*)(red + tok * 4);
            const int pix = pixbase + (tok >> 3) * 128 + (tok & 7);
            out[pix] = (rv.x + rv.y) + (rv.z + rv.w) + outb[0];
        }
    }
}

// ---------------------------------------------------------------------------
extern "C" void kernel_launch(void* const* d_in, const int* in_sizes, int n_in,
                              void* d_out, int out_size, void* d_ws, size_t ws_size,
                              hipStream_t stream)
{
    const float* x      = (const float*)d_in[0];
    const float* cw0    = (const float*)d_in[1];
    const float* cb0    = (const float*)d_in[2];
    const float* pxw0   = (const float*)d_in[3];
    const float* pyw0   = (const float*)d_in[4];
    const float* qkvw0  = (const float*)d_in[5];
    const float* projw0 = (const float*)d_in[6];
    const float* projb0 = (const float*)d_in[7];
    const float* cw1    = (const float*)d_in[8];
    const float* cb1    = (const float*)d_in[9];
    const float* pxw1   = (const float*)d_in[10];
    const float* pyw1   = (const float*)d_in[11];
    const float* qkvw1  = (const float*)d_in[12];
    const float* projw1 = (const float*)d_in[13];
    const float* projb1 = (const float*)d_in[14];
    const float* outw   = (const float*)d_in[15];
    const float* outb   = (const float*)d_in[16];

    const size_t BUF = (size_t)16 * 128 * 128 * 64 * sizeof(float);  // 64 MB slots
    char* ws = (char*)d_ws;
    unsigned short* bufA = (unsigned short*)ws;           // bf16 intermediates
    unsigned short* bufB = (unsigned short*)(ws + BUF);
    char* wsx = ws + 2 * BUF;
    unsigned short* pwb1 = (unsigned short*)(wsx);            // [0,      368640)
    float* pw0           = (float*)(wsx + 369664);            // [369664, 381184)
    unsigned short* qb0  = (unsigned short*)(wsx + 381440);   // [381440, 406016)
    unsigned short* pjb0 = (unsigned short*)(wsx + 406016);   // [406016, 414208)
    unsigned short* qb1  = (unsigned short*)(wsx + 414208);   // [414208, 438784)
    unsigned short* pjb1 = (unsigned short*)(wsx + 438784);   // [438784, 446976)

    repack_kernel<<<860, 256, 0, stream>>>(
        cw0, pxw0, pyw0, cw1, pxw1, pyw1,
        qkvw0, projw0, qkvw1, projw1,
        pwb1, pw0, qb0, pjb0, qb1, pjb1);

    gates1_kernel<<<16384, 256, 0, stream>>>(x, pw0, cb0, bufA);
    attn_kernel<0><<<4096, 256, 0, stream>>>(bufA, qb0, pjb0, projb0, bufB,
                                             nullptr, nullptr, nullptr);
    gates64_kernel<<<4096, 256, 0, stream>>>(bufB, pwb1, cb1, bufA);
    attn_kernel<1><<<4096, 256, 0, stream>>>(bufA, qb1, pjb1, projb1, nullptr,
                                             outw, outb, (float*)d_out);
}

// Round 8
// 341.711 us; speedup vs baseline: 9.0994x; 1.3555x over previous
//
#include <hip/hip_runtime.h>

// ConvLSTM (B=16,H=128,W=128,CIN=1,HID=64, 2 cells, h=c=0 -> f-gate dead)
// Round 8: gates64 weights repacked lane-coalesced (each (g,kk,wave) fragment
// = contiguous 1KB; was 64-line gather per load). Fast tanh in epilogues.
// Pipeline: repack -> gates1 -> attn<0> -> gates64 -> attn<1>(+outconv)

#define DEVFN __device__ __forceinline__

typedef __attribute__((ext_vector_type(8))) short short8;
typedef __attribute__((ext_vector_type(4))) float f32x4;

DEVFN float sigmoidf_(float z) { return 1.0f / (1.0f + __expf(-z)); }

DEVFN float tanhf_(float x) {  // fast tanh; correct limits at +-inf
    float e = __expf(2.0f * x);
    return 1.0f - 2.0f / (e + 1.0f);
}

DEVFN unsigned short f2bf(float f) {  // RNE fp32 -> bf16
    unsigned int u = __builtin_bit_cast(unsigned int, f);
    u += 0x7fffu + ((u >> 16) & 1u);
    return (unsigned short)(u >> 16);
}

DEVFN unsigned pkbf(float a, float b) {  // pack 2 fp32 -> 2 bf16 (RNE)
    return (unsigned)f2bf(a) | ((unsigned)f2bf(b) << 16);
}

// ---------------------------------------------------------------------------
// Repack.
//  pwc (bf16, 184320 el): lane-coalesced gates64 weights.
//    idx = (((g*18+kk)*4 + wv)*64 + lane)*8 + j
//    value = W[g][ch = wv*16+(lane&15)][kcol = kk*32+(lane>>4)*8+j]
//  pw0 (fp32) [5][9][64]; qkv/proj -> bf16 (row-major, unchanged).
// ---------------------------------------------------------------------------
__global__ __launch_bounds__(256) void repack_kernel(
    const float* __restrict__ cw0, const float* __restrict__ pxw0, const float* __restrict__ pyw0,
    const float* __restrict__ cw1, const float* __restrict__ pxw1, const float* __restrict__ pyw1,
    const float* __restrict__ qkvw0, const float* __restrict__ projw0,
    const float* __restrict__ qkvw1, const float* __restrict__ projw1,
    unsigned short* __restrict__ pwc, float* __restrict__ pw0,
    unsigned short* __restrict__ qb0, unsigned short* __restrict__ pjb0,
    unsigned short* __restrict__ qb1, unsigned short* __restrict__ pjb1)
{
    int idx = blockIdx.x * 256 + threadIdx.x;
    if (idx < 184320) {  // 90 * 2048
        int j = idx & 7;
        int lane = (idx >> 3) & 63;
        int wv = (idx >> 9) & 3;
        int t = idx >> 11;          // g*18 + kk
        int kk = t % 18, g = t / 18;
        int c = wv * 16 + (lane & 15);
        int kcol = kk * 32 + (lane >> 4) * 8 + j;
        int pos = kcol >> 6, cin = kcol & 63;
        float v;
        if (g == 0)      v = cw1[((c      ) * 128 + cin) * 9 + pos];  // ci
        else if (g == 1) v = cw1[((128 + c) * 128 + cin) * 9 + pos];  // co
        else if (g == 2) v = cw1[((192 + c) * 128 + cin) * 9 + pos];  // cg
        else if (g == 3) v = pxw1[(c * 64 + cin) * 9 + pos];          // px
        else             v = pyw1[(c * 64 + cin) * 9 + pos];          // py
        pwc[idx] = f2bf(v);
    } else if (idx < 187200) {  // + 5*9*64
        int i2 = idx - 184320;
        int g = i2 / (9 * 64);
        int rem = i2 - g * (9 * 64);
        int pos = rem >> 6, c = rem & 63;
        float v;
        if (g == 0)      v = cw0[(c      ) * 585 + pos];
        else if (g == 1) v = cw0[(128 + c) * 585 + pos];
        else if (g == 2) v = cw0[(192 + c) * 585 + pos];
        else if (g == 3) v = pxw0[c * 9 + pos];
        else             v = pyw0[c * 9 + pos];
        pw0[i2] = v;
    } else if (idx < 187200 + 12288) {
        int i = idx - 187200;           qb0[i] = f2bf(qkvw0[i]);
    } else if (idx < 187200 + 24576) {
        int i = idx - 187200 - 12288;   qb1[i] = f2bf(qkvw1[i]);
    } else if (idx < 187200 + 24576 + 4096) {
        int i = idx - 187200 - 24576;   pjb0[i] = f2bf(projw0[i]);
    } else if (idx < 187200 + 24576 + 8192) {
        int i = idx - 187200 - 28672;   pjb1[i] = f2bf(projw1[i]);
    }
}

// ---------------------------------------------------------------------------
// Layer-0 gates (CIN=1): memory-bound; bf16 output.
// ---------------------------------------------------------------------------
__global__ __launch_bounds__(256) void gates1_kernel(
    const float* __restrict__ x, const float* __restrict__ pw,
    const float* __restrict__ cb, unsigned short* __restrict__ dst)
{
    const int idx = blockIdx.x * 256 + threadIdx.x;
    const int pix = idx >> 4, ch0 = (idx & 15) * 4;
    const int b = pix >> 14, y = (pix >> 7) & 127, xq = pix & 127;

    float a[9];
#pragma unroll
    for (int dy = 0; dy < 3; ++dy)
#pragma unroll
        for (int dx = 0; dx < 3; ++dx) {
            int gy = y + dy - 1, gx = xq + dx - 1;
            a[dy * 3 + dx] = ((unsigned)gy < 128u && (unsigned)gx < 128u)
                ? x[(b * 128 + gy) * 128 + gx] : 0.f;
        }

    float acc[5][4];
#pragma unroll
    for (int g = 0; g < 5; ++g)
#pragma unroll
        for (int u = 0; u < 4; ++u) acc[g][u] = 0.f;

#pragma unroll
    for (int pos = 0; pos < 9; ++pos) {
        const float av = a[pos];
#pragma unroll
        for (int g = 0; g < 5; ++g) {
            const float4 w4 = *(const float4*)(pw + (g * 9 + pos) * 64 + ch0);
            acc[g][0] = fmaf(av, w4.x, acc[g][0]);
            acc[g][1] = fmaf(av, w4.y, acc[g][1]);
            acc[g][2] = fmaf(av, w4.z, acc[g][2]);
            acc[g][3] = fmaf(av, w4.w, acc[g][3]);
        }
    }

    float hv[4];
#pragma unroll
    for (int u = 0; u < 4; ++u) {
        float ci = acc[0][u] + cb[ch0 + u];
        float co = acc[1][u] + cb[128 + ch0 + u];
        float cg = acc[2][u] + cb[192 + ch0 + u];
        float iv = sigmoidf_(ci + acc[3][u]);
        float ov = sigmoidf_(co + acc[4][u]);
        float gv = tanhf_(cg + acc[4][u]);
        hv[u] = ov * tanhf_(iv * gv);
    }
    uint2 o;
    o.x = pkbf(hv[0], hv[1]);
    o.y = pkbf(hv[2], hv[3]);
    *(uint2*)(dst + (size_t)pix * 64 + ch0) = o;
}

// ---------------------------------------------------------------------------
// Layer-1 gates: bf16 MFMA implicit GEMM; lane-coalesced weight loads.
// ---------------------------------------------------------------------------
__global__ __launch_bounds__(256, 2) void gates64_kernel(
    const unsigned short* __restrict__ src, const unsigned short* __restrict__ wtc,
    const float* __restrict__ cb, unsigned short* __restrict__ dst)
{
    __shared__ unsigned short lds[3 * 66 * 64];
    char* const sbase = (char*)lds;

    const int tid = threadIdx.x;
    const int bid = blockIdx.x;
    const int xt = bid & 1, y = (bid >> 1) & 127, b = bid >> 8;
    const int x0 = xt * 64;

    // stage A: bf16 copy, swizzled
    for (int i4 = tid; i4 < 3 * 66 * 8; i4 += 256) {
        int r = i4 / (66 * 8);
        int rem = i4 - r * (66 * 8);
        int xx = rem >> 3, c8 = rem & 7;
        int gy = y + r - 1, gx = x0 + xx - 1;
        uint4 wv = make_uint4(0, 0, 0, 0);
        if ((unsigned)gy < 128u && (unsigned)gx < 128u)
            wv = *(const uint4*)(src + (((size_t)(b * 128 + gy) * 128 + gx) * 64 + c8 * 8));
        int addr = ((r * 66 + xx) * 128 + c8 * 16) ^ ((xx & 7) << 4);
        *(uint4*)(sbase + addr) = wv;
    }
    __syncthreads();

    const int lane = tid & 63;
    const int wv_ = tid >> 6;
    const int r0 = lane & 15;
    const int hi = lane >> 4;
    const int wch = wv_ * 16 + r0;

    // coalesced weight base: fragment (g,kk) = wbase + (g*18+kk)*2048 shorts
    const unsigned short* wbase = wtc + (size_t)(wv_ * 64 + lane) * 8;

    f32x4 acc[4][5];
#pragma unroll
    for (int mt = 0; mt < 4; ++mt)
#pragma unroll
        for (int g = 0; g < 5; ++g) acc[mt][g] = (f32x4){0.f, 0.f, 0.f, 0.f};

#pragma unroll
    for (int kk = 0; kk < 18; ++kk) {
        const int pos = kk >> 1, dy = pos / 3, dx = pos % 3, chalf = kk & 1;
        const int swz = (((r0 + dx) & 7) << 4);
        short8 bfr[5];
#pragma unroll
        for (int g = 0; g < 5; ++g)
            bfr[g] = *(const short8*)(wbase + (g * 18 + kk) * 2048);
        short8 afr[4];
#pragma unroll
        for (int mt = 0; mt < 4; ++mt) {
            const int row = dy * 66 + mt * 16 + r0 + dx;
            const int addr = (row * 128 + chalf * 64 + hi * 16) ^ swz;
            afr[mt] = *(const short8*)(sbase + addr);
        }
#pragma unroll
        for (int mt = 0; mt < 4; ++mt)
#pragma unroll
            for (int g = 0; g < 5; ++g)
                acc[mt][g] = __builtin_amdgcn_mfma_f32_16x16x32_bf16(
                    afr[mt], bfr[g], acc[mt][g], 0, 0, 0);
    }

    const float bci = cb[wch], bco = cb[128 + wch], bcg = cb[192 + wch];
    const int rowbase = (b * 128 + y) * 128 + x0;
#pragma unroll
    for (int mt = 0; mt < 4; ++mt) {
#pragma unroll
        for (int rg = 0; rg < 4; ++rg) {
            const int px_i = mt * 16 + hi * 4 + rg;
            float ci = acc[mt][0][rg] + bci;
            float co = acc[mt][1][rg] + bco;
            float cg = acc[mt][2][rg] + bcg;
            float pxv = acc[mt][3][rg];
            float pyv = acc[mt][4][rg];
            float iv = sigmoidf_(ci + pxv);
            float ov = sigmoidf_(co + pyv);
            float gv = tanhf_(cg + pyv);
            dst[(size_t)(rowbase + px_i) * 64 + wch] = f2bf(ov * tanhf_(iv * gv));
        }
    }
}

// ---------------------------------------------------------------------------
// Window attention (full bf16 MFMA). FUSE=1: fold 1x1 outconv into epilogue.
// ---------------------------------------------------------------------------
template <int FUSE>
__global__ __launch_bounds__(256, 4) void attn_kernel(
    const unsigned short* __restrict__ src,    // NHWC bf16 [16,128,128,64]
    const unsigned short* __restrict__ qkvwb,  // [192][64] bf16
    const unsigned short* __restrict__ projwb, // [64][64] bf16
    const float* __restrict__ projb,           // [64]
    unsigned short* __restrict__ dst,          // NHWC bf16 (FUSE=0)
    const float* __restrict__ outw,            // [64] (FUSE=1)
    const float* __restrict__ outb,            // [1]  (FUSE=1)
    float* __restrict__ out)                   // [16,128,128,1] (FUSE=1)
{
    __shared__ char sm[32768];
    char* const Xs = sm;            // [64 tok][128B] swz ((tok&7)<<4)
    char* const Xo = sm + 8192;     // [64 tok][128B] swz ((tok&7)<<4)
    char* const Qs = sm + 16384;    // [64 tok][48B]
    char* const Ks = sm + 19456;    // [64 tok][48B]
    char* const VT = sm + 22528;    // [16 d][128B] swz; reused as red[64][4] f32
    char* const Ps = sm + 24576;    // [64 q][128B] swz

    const int tid = threadIdx.x;
    const int lane = tid & 63;
    const int w = __builtin_amdgcn_readfirstlane(tid >> 6);
    const int lo = lane & 15, hi = lane >> 4;
    const int wid = blockIdx.x;
    const int b = wid >> 8, rem = wid & 255, wy = rem >> 4, wx = rem & 15;
    const int pixbase = (b * 128 + wy * 8) * 128 + wx * 8;

    // ---- stage X: bf16 copy, swizzled ----
    {
        const int t = tid >> 2, c0 = (tid & 3) * 16;
        const int pix = pixbase + (t >> 3) * 128 + (t & 7);
        const uint4* sp = (const uint4*)(src + (size_t)pix * 64 + c0);
        uint4 w0 = sp[0], w1 = sp[1];
        const int a = t * 128 + c0 * 2, sz = (t & 7) << 4;
        *(uint4*)(Xs + (a ^ sz)) = w0;
        *(uint4*)(Xs + ((a + 16) ^ sz)) = w1;
    }
    __syncthreads();

    const int trow = w * 16 + lo;
    const int tswz = (lo & 7) << 4;

    for (int h = 0; h < 4; ++h) {
        // ---- qkv for head h ----
        f32x4 cq = {0.f, 0.f, 0.f, 0.f}, ck = cq, cv = cq;
#pragma unroll
        for (int ks = 0; ks < 2; ++ks) {
            const int koff = hi * 8 + ks * 32;
            short8 xb = *(const short8*)(Xs + ((trow * 128 + koff * 2) ^ tswz));
            short8 aq = *(const short8*)(qkvwb + (h * 16 + lo) * 64 + koff);
            short8 ak = *(const short8*)(qkvwb + (64 + h * 16 + lo) * 64 + koff);
            short8 bv = *(const short8*)(qkvwb + (128 + h * 16 + lo) * 64 + koff);
            cq = __builtin_amdgcn_mfma_f32_16x16x32_bf16(aq, xb, cq, 0, 0, 0);
            ck = __builtin_amdgcn_mfma_f32_16x16x32_bf16(ak, xb, ck, 0, 0, 0);
            cv = __builtin_amdgcn_mfma_f32_16x16x32_bf16(xb, bv, cv, 0, 0, 0);
        }
        {
            uint2 qw, kw, vw;
            qw.x = pkbf(cq[0] * 0.125f, cq[1] * 0.125f);
            qw.y = pkbf(cq[2] * 0.125f, cq[3] * 0.125f);
            kw.x = pkbf(ck[0], ck[1]); kw.y = pkbf(ck[2], ck[3]);
            *(uint2*)(Qs + trow * 48 + hi * 8) = qw;
            *(uint2*)(Ks + trow * 48 + hi * 8) = kw;
            vw.x = pkbf(cv[0], cv[1]); vw.y = pkbf(cv[2], cv[3]);
            *(uint2*)(VT + ((lo * 128 + (w * 16 + hi * 4) * 2) ^ ((lo & 7) << 4))) = vw;
        }
        __syncthreads();  // barrier A

        // ---- scores (duplicated k-halves; Q pre-scaled 0.125) ----
        short8 bq = *(const short8*)(Qs + trow * 48 + (hi & 1) * 16);
        f32x4 st[4];
#pragma unroll
        for (int mt = 0; mt < 4; ++mt) {
            short8 ak2 = *(const short8*)(Ks + (mt * 16 + lo) * 48 + (hi & 1) * 16);
            f32x4 z = {0.f, 0.f, 0.f, 0.f};
            st[mt] = __builtin_amdgcn_mfma_f32_16x16x32_bf16(ak2, bq, z, 0, 0, 0);
        }
        float mx = -1e30f;
#pragma unroll
        for (int mt = 0; mt < 4; ++mt)
#pragma unroll
            for (int r = 0; r < 4; ++r) mx = fmaxf(mx, st[mt][r]);
        mx = fmaxf(mx, __shfl_xor(mx, 16));
        mx = fmaxf(mx, __shfl_xor(mx, 32));
        float pv[16];
        float sum = 0.f;
#pragma unroll
        for (int mt = 0; mt < 4; ++mt)
#pragma unroll
            for (int r = 0; r < 4; ++r) {
                float e = __expf(st[mt][r] - mx);
                pv[mt * 4 + r] = e;
                sum += e;
            }
        sum += __shfl_xor(sum, 16);
        sum += __shfl_xor(sum, 32);
        const float rs = 1.0f / sum;
#pragma unroll
        for (int mt = 0; mt < 4; ++mt) {
            uint2 pw_;
            pw_.x = pkbf(pv[mt * 4 + 0] * rs, pv[mt * 4 + 1] * rs);
            pw_.y = pkbf(pv[mt * 4 + 2] * rs, pv[mt * 4 + 3] * rs);
            *(uint2*)(Ps + ((trow * 128 + (mt * 16 + hi * 4) * 2) ^ tswz)) = pw_;
        }

        // ---- PV: O^T = V^T · P^T ----
        f32x4 ot = {0.f, 0.f, 0.f, 0.f};
#pragma unroll
        for (int ks = 0; ks < 2; ++ks) {
            const int ko = (hi * 8 + ks * 32) * 2;
            short8 av = *(const short8*)(VT + ((lo * 128 + ko) ^ ((lo & 7) << 4)));
            short8 bp = *(const short8*)(Ps + ((trow * 128 + ko) ^ tswz));
            ot = __builtin_amdgcn_mfma_f32_16x16x32_bf16(av, bp, ot, 0, 0, 0);
        }
        {
            uint2 ow_;
            ow_.x = pkbf(ot[0], ot[1]); ow_.y = pkbf(ot[2], ot[3]);
            *(uint2*)(Xo + ((trow * 128 + (h * 16 + hi * 4) * 2) ^ tswz)) = ow_;
        }
        __syncthreads();  // barrier B
    }

    // ---- proj ----
    f32x4 cy[4];
#pragma unroll
    for (int mt = 0; mt < 4; ++mt) cy[mt] = (f32x4){0.f, 0.f, 0.f, 0.f};
#pragma unroll
    for (int ks = 0; ks < 2; ++ks) {
        const int koff = hi * 8 + ks * 32;
        short8 bw = *(const short8*)(projwb + (w * 16 + lo) * 64 + koff);
#pragma unroll
        for (int mt = 0; mt < 4; ++mt) {
            short8 ax = *(const short8*)(Xo + (((mt * 16 + lo) * 128 + koff * 2) ^ ((lo & 7) << 4)));
            cy[mt] = __builtin_amdgcn_mfma_f32_16x16x32_bf16(ax, bw, cy[mt], 0, 0, 0);
        }
    }
    const float pb = projb[w * 16 + lo];

    if constexpr (FUSE == 0) {
#pragma unroll
        for (int mt = 0; mt < 4; ++mt) {
#pragma unroll
            for (int r = 0; r < 4; ++r) {
                const int tok = mt * 16 + hi * 4 + r;
                const int pix = pixbase + (tok >> 3) * 128 + (tok & 7);
                dst[(size_t)pix * 64 + w * 16 + lo] = f2bf(cy[mt][r] + pb);
            }
        }
    } else {
        // fused 1x1 outconv: out[tok] = sum_ch (Y[tok][ch]) * ow[ch] + ob
        const float owv = outw[w * 16 + lo];
        float* red = (float*)VT;  // [64 tok][4 waves]
#pragma unroll
        for (int mt = 0; mt < 4; ++mt) {
#pragma unroll
            for (int r = 0; r < 4; ++r) {
                float s = (cy[mt][r] + pb) * owv;
                s += __shfl_xor(s, 1);
                s += __shfl_xor(s, 2);
                s += __shfl_xor(s, 4);
                s += __shfl_xor(s, 8);
                if (lo == 0) red[(mt * 16 + hi * 4 + r) * 4 + w] = s;
            }
        }
        __syncthreads();
        if (tid < 64) {
            const int tok = tid;
            float4 rv = *(const float4*)(red + tok * 4);
            const int pix = pixbase + (tok >> 3) * 128 + (tok & 7);
            out[pix] = (rv.x + rv.y) + (rv.z + rv.w) + outb[0];
        }
    }
}

// ---------------------------------------------------------------------------
extern "C" void kernel_launch(void* const* d_in, const int* in_sizes, int n_in,
                              void* d_out, int out_size, void* d_ws, size_t ws_size,
                              hipStream_t stream)
{
    const float* x      = (const float*)d_in[0];
    const float* cw0    = (const float*)d_in[1];
    const float* cb0    = (const float*)d_in[2];
    const float* pxw0   = (const float*)d_in[3];
    const float* pyw0   = (const float*)d_in[4];
    const float* qkvw0  = (const float*)d_in[5];
    const float* projw0 = (const float*)d_in[6];
    const float* projb0 = (const float*)d_in[7];
    const float* cw1    = (const float*)d_in[8];
    const float* cb1    = (const float*)d_in[9];
    const float* pxw1   = (const float*)d_in[10];
    const float* pyw1   = (const float*)d_in[11];
    const float* qkvw1  = (const float*)d_in[12];
    const float* projw1 = (const float*)d_in[13];
    const float* projb1 = (const float*)d_in[14];
    const float* outw   = (const float*)d_in[15];
    const float* outb   = (const float*)d_in[16];

    const size_t BUF = (size_t)16 * 128 * 128 * 64 * sizeof(float);  // 64 MB slots
    char* ws = (char*)d_ws;
    unsigned short* bufA = (unsigned short*)ws;           // bf16 intermediates
    unsigned short* bufB = (unsigned short*)(ws + BUF);
    char* wsx = ws + 2 * BUF;
    unsigned short* pwc  = (unsigned short*)(wsx);            // [0,      368640)
    float* pw0           = (float*)(wsx + 369664);            // [369664, 381184)
    unsigned short* qb0  = (unsigned short*)(wsx + 381440);   // [381440, 406016)
    unsigned short* pjb0 = (unsigned short*)(wsx + 406016);   // [406016, 414208)
    unsigned short* qb1  = (unsigned short*)(wsx + 414208);   // [414208, 438784)
    unsigned short* pjb1 = (unsigned short*)(wsx + 438784);   // [438784, 446976)

    repack_kernel<<<860, 256, 0, stream>>>(
        cw0, pxw0, pyw0, cw1, pxw1, pyw1,
        qkvw0, projw0, qkvw1, projw1,
        pwc, pw0, qb0, pjb0, qb1, pjb1);

    gates1_kernel<<<16384, 256, 0, stream>>>(x, pw0, cb0, bufA);
    attn_kernel<0><<<4096, 256, 0, stream>>>(bufA, qb0, pjb0, projb0, bufB,
                                             nullptr, nullptr, nullptr);
    gates64_kernel<<<4096, 256, 0, stream>>>(bufB, pwc, cb1, bufA);
    attn_kernel<1><<<4096, 256, 0, stream>>>(bufA, qb1, pjb1, projb1, nullptr,
                                             outw, outb, (float*)d_out);
}